// Round 1
// baseline (3233.715 us; speedup 1.0000x reference)
//
#include <hip/hip_runtime.h>
#include <cmath>

// Quaternion self-attention, f32 baseline.
// y[4096,1024] ++ w_last[4096,4096] -> d_out (f32).
// ws: Q,K,V each 4096x1024 f32 (50.3 MB total).

#define BM 64
#define BN 64
#define BKT 32
#define LDP 68  // padded LDS row length (floats): 64 + 4, keeps float4 alignment

// C[M,N] = A[M,K] * B'[N,K]^T where B' applies a per-256-chunk column
// permutation + sign to B (Hamilton-product structure). perm_packed: 2 bits
// per chunk t -> source chunk; sign_packed: bit t set -> negate.
__global__ __launch_bounds__(256) void gemm_abt_f32(
    const float* __restrict__ A, const float* __restrict__ B, float* __restrict__ C,
    int K, int lda, int ldb, int ldc, int perm_packed, int sign_packed)
{
    __shared__ float As[BKT][LDP];
    __shared__ float Bs[BKT][LDP];
    const int tid = threadIdx.x;
    const int tx = tid & 15, ty = tid >> 4;
    const int row0 = blockIdx.y * BM;
    const int col0 = blockIdx.x * BN;
    float acc[4][4] = {};

    for (int k0 = 0; k0 < K; k0 += BKT) {
        const int t = k0 >> 8;
        const int p = (perm_packed >> (2 * t)) & 3;
        const float s = ((sign_packed >> t) & 1) ? -1.0f : 1.0f;
        const int kpB = (p << 8) | (k0 & 255);
        #pragma unroll
        for (int l = 0; l < 2; ++l) {
            int idx = tid + l * 256;      // 512 float4 slots = 64 rows x 32 k
            int r = idx >> 3;
            int kc = (idx & 7) << 2;
            float4 v = *reinterpret_cast<const float4*>(&A[(size_t)(row0 + r) * lda + k0 + kc]);
            As[kc + 0][r] = v.x; As[kc + 1][r] = v.y; As[kc + 2][r] = v.z; As[kc + 3][r] = v.w;
        }
        #pragma unroll
        for (int l = 0; l < 2; ++l) {
            int idx = tid + l * 256;
            int r = idx >> 3;
            int kc = (idx & 7) << 2;
            float4 v = *reinterpret_cast<const float4*>(&B[(size_t)(col0 + r) * ldb + kpB + kc]);
            Bs[kc + 0][r] = s * v.x; Bs[kc + 1][r] = s * v.y; Bs[kc + 2][r] = s * v.z; Bs[kc + 3][r] = s * v.w;
        }
        __syncthreads();
        #pragma unroll
        for (int kk = 0; kk < BKT; ++kk) {
            float4 a4 = *reinterpret_cast<const float4*>(&As[kk][ty << 2]);
            float4 b4 = *reinterpret_cast<const float4*>(&Bs[kk][tx << 2]);
            float a[4] = {a4.x, a4.y, a4.z, a4.w};
            float b[4] = {b4.x, b4.y, b4.z, b4.w};
            #pragma unroll
            for (int i = 0; i < 4; ++i)
                #pragma unroll
                for (int j = 0; j < 4; ++j)
                    acc[i][j] = fmaf(a[i], b[j], acc[i][j]);
        }
        __syncthreads();
    }
    #pragma unroll
    for (int i = 0; i < 4; ++i) {
        float4 o = make_float4(acc[i][0], acc[i][1], acc[i][2], acc[i][3]);
        *reinterpret_cast<float4*>(&C[(size_t)(row0 + (ty << 2) + i) * ldc + col0 + (tx << 2)]) = o;
    }
}

// C[M,N] = A[M,K] * B[K,N]  (PV product; B row-major along N)
__global__ __launch_bounds__(256) void gemm_ab_f32(
    const float* __restrict__ A, const float* __restrict__ B, float* __restrict__ C,
    int K, int lda, int ldb, int ldc)
{
    __shared__ float As[BKT][LDP];
    __shared__ float Bs[BKT][LDP];
    const int tid = threadIdx.x;
    const int tx = tid & 15, ty = tid >> 4;
    const int row0 = blockIdx.y * BM;
    const int col0 = blockIdx.x * BN;
    float acc[4][4] = {};

    for (int k0 = 0; k0 < K; k0 += BKT) {
        #pragma unroll
        for (int l = 0; l < 2; ++l) {
            int idx = tid + l * 256;
            int r = idx >> 3;
            int kc = (idx & 7) << 2;
            float4 v = *reinterpret_cast<const float4*>(&A[(size_t)(row0 + r) * lda + k0 + kc]);
            As[kc + 0][r] = v.x; As[kc + 1][r] = v.y; As[kc + 2][r] = v.z; As[kc + 3][r] = v.w;
        }
        #pragma unroll
        for (int l = 0; l < 2; ++l) {
            int idx = tid + l * 256;      // 512 float4 = 32 k-rows x 64 cols
            int kc = idx >> 4;
            int j4 = (idx & 15) << 2;
            float4 v = *reinterpret_cast<const float4*>(&B[(size_t)(k0 + kc) * ldb + col0 + j4]);
            *reinterpret_cast<float4*>(&Bs[kc][j4]) = v;
        }
        __syncthreads();
        #pragma unroll
        for (int kk = 0; kk < BKT; ++kk) {
            float4 a4 = *reinterpret_cast<const float4*>(&As[kk][ty << 2]);
            float4 b4 = *reinterpret_cast<const float4*>(&Bs[kk][tx << 2]);
            float a[4] = {a4.x, a4.y, a4.z, a4.w};
            float b[4] = {b4.x, b4.y, b4.z, b4.w};
            #pragma unroll
            for (int i = 0; i < 4; ++i)
                #pragma unroll
                for (int j = 0; j < 4; ++j)
                    acc[i][j] = fmaf(a[i], b[j], acc[i][j]);
        }
        __syncthreads();
    }
    #pragma unroll
    for (int i = 0; i < 4; ++i) {
        float4 o = make_float4(acc[i][0], acc[i][1], acc[i][2], acc[i][3]);
        *reinterpret_cast<float4*>(&C[(size_t)(row0 + (ty << 2) + i) * ldc + col0 + (tx << 2)]) = o;
    }
}

// In-place row softmax over N=4096 columns. One block (256 thr) per row;
// 16 values/thread kept in registers (4x float4).
__global__ __launch_bounds__(256) void softmax_rows(float* __restrict__ Wm, int N)
{
    const int tid = threadIdx.x;
    float* rp = Wm + (size_t)blockIdx.x * N;
    __shared__ float red[4];

    float4 v[4];
    float lmax = -INFINITY;
    #pragma unroll
    for (int l = 0; l < 4; ++l) {
        v[l] = *reinterpret_cast<const float4*>(&rp[(size_t)(l * 256 + tid) * 4]);
        lmax = fmaxf(lmax, fmaxf(fmaxf(v[l].x, v[l].y), fmaxf(v[l].z, v[l].w)));
    }
    #pragma unroll
    for (int off = 1; off < 64; off <<= 1)
        lmax = fmaxf(lmax, __shfl_xor(lmax, off, 64));
    if ((tid & 63) == 0) red[tid >> 6] = lmax;
    __syncthreads();
    const float m = fmaxf(fmaxf(red[0], red[1]), fmaxf(red[2], red[3]));
    __syncthreads();

    float ssum = 0.0f;
    #pragma unroll
    for (int l = 0; l < 4; ++l) {
        v[l].x = expf(v[l].x - m); v[l].y = expf(v[l].y - m);
        v[l].z = expf(v[l].z - m); v[l].w = expf(v[l].w - m);
        ssum += v[l].x + v[l].y + v[l].z + v[l].w;
    }
    #pragma unroll
    for (int off = 1; off < 64; off <<= 1)
        ssum += __shfl_xor(ssum, off, 64);
    if ((tid & 63) == 0) red[tid >> 6] = ssum;
    __syncthreads();
    const float inv = 1.0f / (red[0] + red[1] + red[2] + red[3]);

    #pragma unroll
    for (int l = 0; l < 4; ++l) {
        float4 o = make_float4(v[l].x * inv, v[l].y * inv, v[l].z * inv, v[l].w * inv);
        *reinterpret_cast<float4*>(&rp[(size_t)(l * 256 + tid) * 4]) = o;
    }
}

extern "C" void kernel_launch(void* const* d_in, const int* in_sizes, int n_in,
                              void* d_out, int out_size, void* d_ws, size_t ws_size,
                              hipStream_t stream)
{
    const int n = 4096, d = 1024;
    const float* x  = (const float*)d_in[0];
    const float* WQ = (const float*)d_in[1];
    const float* WK = (const float*)d_in[2];
    const float* WV = (const float*)d_in[3];

    float* y = (float*)d_out;                       // [4096,1024]
    float* w = y + (size_t)n * d;                   // [4096,4096], also scratch for comps 0-2
    float* Q = (float*)d_ws;                        // [4096,1024]
    float* K = Q + (size_t)n * d;
    float* V = K + (size_t)n * d;

    dim3 blk(256);

    // Q/K/V = x @ W^T  (identity perm, no signs)
    dim3 gqkv(d / BN, n / BM);
    gemm_abt_f32<<<gqkv, blk, 0, stream>>>(x, WQ, Q, d, d, d, d, 0xE4, 0x0);
    gemm_abt_f32<<<gqkv, blk, 0, stream>>>(x, WK, K, d, d, d, d, 0xE4, 0x0);
    gemm_abt_f32<<<gqkv, blk, 0, stream>>>(x, WV, V, d, d, d, d, 0xE4, 0x0);

    // Hamilton-product component tables (q-chunk t pairs k-chunk perm[t], sign)
    // c0 (r): perm {0,1,2,3} sign {+,-,-,-}; c1 (i): {1,0,3,2} {+,+,+,-}
    // c2 (j): {2,3,0,1} {+,-,+,+};          c3 (k): {3,2,1,0} {+,+,-,+}
    const int permv[4] = {0xE4, 0xB1, 0x4E, 0x1B};
    const int signv[4] = {0x0E, 0x08, 0x02, 0x04};

    dim3 gl(n / BN, n / BM);
    dim3 gpv(256 / BN, n / BM);
    for (int c = 0; c < 4; ++c) {
        // logits into w-region (comp 3 runs last -> its softmax stays as output)
        gemm_abt_f32<<<gl, blk, 0, stream>>>(Q, K, w, d, d, d, n, permv[c], signv[c]);
        softmax_rows<<<n, blk, 0, stream>>>(w, n);
        gemm_ab_f32<<<gpv, blk, 0, stream>>>(w, V + (size_t)c * 256, y + (size_t)c * 256,
                                             n, n, d, d);
    }
}

// Round 2
// 1314.024 us; speedup vs baseline: 2.4609x; 2.4609x over previous
//
#include <hip/hip_runtime.h>
#include <hip/hip_bf16.h>
#include <cmath>

typedef __attribute__((ext_vector_type(8))) short short8;
typedef __attribute__((ext_vector_type(4))) float f32x4;
typedef unsigned short u16;

__device__ __forceinline__ u16 f2bf(float f) {
    unsigned u = __float_as_uint(f);
    u = u + 0x7FFFu + ((u >> 16) & 1u);
    return (u16)(u >> 16);
}
__device__ __forceinline__ float bf2f(u16 b) {
    return __uint_as_float(((unsigned)b) << 16);
}

#define GLD16(g, l)                                                              \
    __builtin_amdgcn_global_load_lds(                                            \
        (const __attribute__((address_space(1))) unsigned int*)(g),              \
        (__attribute__((address_space(3))) unsigned int*)(l), 16, 0, 0)

// split f32 [R,1024] -> bf16 [R,2048] = [hi | lo]; grid = R blocks x 256 thr
__global__ __launch_bounds__(256) void split_rows(const float* __restrict__ in,
                                                  u16* __restrict__ out) {
    int idx = blockIdx.x * 256 + threadIdx.x;   // one float4 per thread
    int r = idx >> 8, s = idx & 255;
    float4 v = reinterpret_cast<const float4*>(in)[idx];
    ushort4 hi, lo;
    hi.x = f2bf(v.x); lo.x = f2bf(v.x - bf2f(hi.x));
    hi.y = f2bf(v.y); lo.y = f2bf(v.y - bf2f(hi.y));
    hi.z = f2bf(v.z); lo.z = f2bf(v.z - bf2f(hi.z));
    hi.w = f2bf(v.w); lo.w = f2bf(v.w - bf2f(hi.w));
    u16* row = out + (size_t)r * 2048;
    reinterpret_cast<ushort4*>(row)[s] = hi;
    reinterpret_cast<ushort4*>(row + 1024)[s] = lo;
}

// C = A * B^T, bf16 MFMA 16x16x32, m97 structure (BK=64, gload_lds width 16).
// SPLIT3: K2=3*1024, slices {A:hi,hi,lo}x{B:hi,lo,hi} over [hi|lo] storage.
// PERM:   Hamilton per-256-chunk column perm on B; sign via Bneg copy.
// SA32:   A is f32, reg-staged + converted to plain bf16 (PV path).
// EPI: 0=f32 store; 1=split hi/lo bf16 [M,2048]; 2=split + negated copy -> C2;
//      3=plain bf16 transposed store (C[gc*4096+gr], for Vt).
template<int BM, int BN, bool SPLIT3, bool PERM, bool SA32, int EPI>
__global__ __launch_bounds__(256) void mfma_gemm(
    const void* __restrict__ Av, const u16* __restrict__ B,
    const u16* __restrict__ Bneg, void* __restrict__ Cv, u16* __restrict__ C2,
    int K2, int lda, int ldb, int ldc, int perm_packed, int sign_packed)
{
    constexpr int WTM = BM / 2, WTN = BN / 2;
    constexpr int FM = WTM / 16, FN = WTN / 16;
    __shared__ u16 As[BM][64];
    __shared__ u16 Bs[BN][64];
    const int tid = threadIdx.x;
    const int l = tid & 63, w = tid >> 6;
    const int wr = w >> 1, wc = w & 1;
    const int row0 = blockIdx.y * BM, col0 = blockIdx.x * BN;
    const int r8 = l >> 3;          // row within an 8-row gload group
    const int cb = (l & 7) * 8;     // bf16 col within 64
    const int lr = l & 15, lh = l >> 4;

    const u16* A = (const u16*)Av;
    const float* Af = (const float*)Av;

    f32x4 acc[FM][FN] = {};

    for (int k0 = 0; k0 < K2; k0 += 64) {
        int kA, kB;
        const u16* Bsrc = B;
        if (SPLIT3) {
            int sl = k0 >> 10;
            int kk = k0 & 1023;
            kA = kk + (sl == 2 ? 1024 : 0);
            if (PERM) {
                int t = kk >> 8;
                int p = (perm_packed >> (2 * t)) & 3;
                if ((sign_packed >> t) & 1) Bsrc = Bneg;
                kB = (sl == 1 ? 1024 : 0) + (p << 8) + (kk & 255);
            } else {
                kB = kk + (sl == 1 ? 1024 : 0);
            }
        } else { kA = k0; kB = k0; }

        __syncthreads();
        if (SA32) {
            #pragma unroll
            for (int i = 0; i < BM / 16; ++i) {   // BM rows x 16 float4-slots
                int idx = tid + i * 256;
                int r = idx >> 4, s4 = idx & 15;
                float4 v = *reinterpret_cast<const float4*>(
                    &Af[(size_t)(row0 + r) * lda + kA + s4 * 4]);
                ushort4 h;
                h.x = f2bf(v.x); h.y = f2bf(v.y); h.z = f2bf(v.z); h.w = f2bf(v.w);
                *reinterpret_cast<ushort4*>(&As[r][s4 * 4]) = h;
            }
        } else {
            #pragma unroll
            for (int i = 0; i < BM / 32; ++i) {
                int r0 = (w * (BM / 32) + i) * 8;
                GLD16(&A[(size_t)(row0 + r0 + r8) * lda + kA + cb], &As[r0][0]);
            }
        }
        #pragma unroll
        for (int i = 0; i < BN / 32; ++i) {
            int r0 = (w * (BN / 32) + i) * 8;
            GLD16(&Bsrc[(size_t)(col0 + r0 + r8) * ldb + kB + cb], &Bs[r0][0]);
        }
        __syncthreads();

        #pragma unroll
        for (int h = 0; h < 2; ++h) {
            short8 af[FM], bfr[FN];
            #pragma unroll
            for (int m = 0; m < FM; ++m)
                af[m] = *reinterpret_cast<const short8*>(
                    &As[wr * WTM + m * 16 + lr][h * 32 + lh * 8]);
            #pragma unroll
            for (int nn = 0; nn < FN; ++nn)
                bfr[nn] = *reinterpret_cast<const short8*>(
                    &Bs[wc * WTN + nn * 16 + lr][h * 32 + lh * 8]);
            #pragma unroll
            for (int m = 0; m < FM; ++m)
                #pragma unroll
                for (int nn = 0; nn < FN; ++nn)
                    acc[m][nn] = __builtin_amdgcn_mfma_f32_16x16x32_bf16(
                        af[m], bfr[nn], acc[m][nn], 0, 0, 0);
        }
    }

    #pragma unroll
    for (int m = 0; m < FM; ++m) {
        #pragma unroll
        for (int nn = 0; nn < FN; ++nn) {
            int gr = row0 + wr * WTM + m * 16 + lh * 4;
            int gc = col0 + wc * WTN + nn * 16 + lr;
            f32x4 v = acc[m][nn];
            if (EPI == 0) {
                float* C = (float*)Cv;
                #pragma unroll
                for (int j = 0; j < 4; ++j)
                    C[(size_t)(gr + j) * ldc + gc] = v[j];
            } else if (EPI == 1 || EPI == 2) {
                u16* C = (u16*)Cv;
                #pragma unroll
                for (int j = 0; j < 4; ++j) {
                    u16 hi = f2bf(v[j]);
                    u16 lo = f2bf(v[j] - bf2f(hi));
                    size_t o = (size_t)(gr + j) * 2048 + gc;
                    C[o] = hi; C[o + 1024] = lo;
                    if (EPI == 2) { C2[o] = hi ^ 0x8000; C2[o + 1024] = lo ^ 0x8000; }
                }
            } else if (EPI == 3) {
                u16* C = (u16*)Cv;
                ushort4 o;
                o.x = f2bf(v[0]); o.y = f2bf(v[1]); o.z = f2bf(v[2]); o.w = f2bf(v[3]);
                *reinterpret_cast<ushort4*>(&C[(size_t)gc * 4096 + gr]) = o;
            }
        }
    }
}

// In-place row softmax over N=4096 columns; one 256-thr block per row.
__global__ __launch_bounds__(256) void softmax_rows(float* __restrict__ Wm, int N)
{
    const int tid = threadIdx.x;
    float* rp = Wm + (size_t)blockIdx.x * N;
    __shared__ float red[4];

    float4 v[4];
    float lmax = -INFINITY;
    #pragma unroll
    for (int l = 0; l < 4; ++l) {
        v[l] = *reinterpret_cast<const float4*>(&rp[(size_t)(l * 256 + tid) * 4]);
        lmax = fmaxf(lmax, fmaxf(fmaxf(v[l].x, v[l].y), fmaxf(v[l].z, v[l].w)));
    }
    #pragma unroll
    for (int off = 1; off < 64; off <<= 1)
        lmax = fmaxf(lmax, __shfl_xor(lmax, off, 64));
    if ((tid & 63) == 0) red[tid >> 6] = lmax;
    __syncthreads();
    const float m = fmaxf(fmaxf(red[0], red[1]), fmaxf(red[2], red[3]));
    __syncthreads();

    float ssum = 0.0f;
    #pragma unroll
    for (int l = 0; l < 4; ++l) {
        v[l].x = expf(v[l].x - m); v[l].y = expf(v[l].y - m);
        v[l].z = expf(v[l].z - m); v[l].w = expf(v[l].w - m);
        ssum += v[l].x + v[l].y + v[l].z + v[l].w;
    }
    #pragma unroll
    for (int off = 1; off < 64; off <<= 1)
        ssum += __shfl_xor(ssum, off, 64);
    if ((tid & 63) == 0) red[tid >> 6] = ssum;
    __syncthreads();
    const float inv = 1.0f / (red[0] + red[1] + red[2] + red[3]);

    #pragma unroll
    for (int l = 0; l < 4; ++l) {
        float4 o = make_float4(v[l].x * inv, v[l].y * inv, v[l].z * inv, v[l].w * inv);
        *reinterpret_cast<float4*>(&rp[(size_t)(l * 256 + tid) * 4]) = o;
    }
}

extern "C" void kernel_launch(void* const* d_in, const int* in_sizes, int n_in,
                              void* d_out, int out_size, void* d_ws, size_t ws_size,
                              hipStream_t stream)
{
    const int n = 4096, d = 1024;
    const float* x  = (const float*)d_in[0];
    const float* WQ = (const float*)d_in[1];
    const float* WK = (const float*)d_in[2];
    const float* WV = (const float*)d_in[3];

    float* y = (float*)d_out;                  // [4096,1024]
    float* w = y + (size_t)n * d;              // [4096,4096] logits/softmax (comp 3 = output)

    u16* xs  = (u16*)d_ws;                     // [4096,2048]
    u16* WQs = xs  + (size_t)n * 2048;         // [1024,2048]
    u16* WKs = WQs + (size_t)d * 2048;
    u16* WVs = WKs + (size_t)d * 2048;
    u16* Qs  = WVs + (size_t)d * 2048;         // [4096,2048]
    u16* Ks  = Qs  + (size_t)n * 2048;
    u16* Ksn = Ks  + (size_t)n * 2048;         // -Ks
    u16* Vt  = Ksn + (size_t)n * 2048;         // [1024,4096] bf16 V^T
    // total ws: 88.1 MB

    split_rows<<<n, 256, 0, stream>>>(x, xs);
    split_rows<<<d, 256, 0, stream>>>(WQ, WQs);
    split_rows<<<d, 256, 0, stream>>>(WK, WKs);
    split_rows<<<d, 256, 0, stream>>>(WV, WVs);

    // QKV projections: [4096,1024] = xs * Ws^T (split-bf16, K2=3072)
    dim3 blk(256);
    dim3 gq(d / 128, n / 128);
    mfma_gemm<128,128,true,false,false,1><<<gq, blk, 0, stream>>>(
        xs, WQs, nullptr, Qs, nullptr, 3072, 2048, 2048, 0, 0, 0);
    mfma_gemm<128,128,true,false,false,2><<<gq, blk, 0, stream>>>(
        xs, WKs, nullptr, Ks, Ksn, 3072, 2048, 2048, 0, 0, 0);
    mfma_gemm<128,128,true,false,false,3><<<gq, blk, 0, stream>>>(
        xs, WVs, nullptr, Vt, nullptr, 3072, 2048, 2048, 0, 0, 0);

    // Hamilton tables: q-chunk t pairs k-chunk perm[t] with sign[t]
    const int permv[4] = {0xE4, 0xB1, 0x4E, 0x1B};
    const int signv[4] = {0x0E, 0x08, 0x02, 0x04};

    dim3 gl(n / 128, n / 128);
    dim3 gpv(256 / 64, n / 64);
    for (int c = 0; c < 4; ++c) {
        mfma_gemm<128,128,true,true,false,0><<<gl, blk, 0, stream>>>(
            Qs, Ks, Ksn, w, nullptr, 3072, 2048, 2048, n, permv[c], signv[c]);
        softmax_rows<<<n, blk, 0, stream>>>(w, n);
        mfma_gemm<64,64,false,false,true,0><<<gpv, blk, 0, stream>>>(
            w, Vt + (size_t)c * 256 * 4096, nullptr, y + (size_t)c * 256, nullptr,
            4096, 4096, 4096, d, 0, 0);
    }
}

// Round 3
// 1074.325 us; speedup vs baseline: 3.0100x; 1.2231x over previous
//
#include <hip/hip_runtime.h>
#include <cmath>

typedef __attribute__((ext_vector_type(8))) short short8;
typedef __attribute__((ext_vector_type(4))) float f32x4;
typedef unsigned short u16;

__device__ __forceinline__ u16 f2bf(float f) {
    unsigned u = __float_as_uint(f);
    u = u + 0x7FFFu + ((u >> 16) & 1u);
    return (u16)(u >> 16);
}
__device__ __forceinline__ float bf2f(u16 b) {
    return __uint_as_float(((unsigned)b) << 16);
}

#define GLD16(g, l)                                                              \
    __builtin_amdgcn_global_load_lds(                                            \
        (const __attribute__((address_space(1))) unsigned int*)(g),              \
        (__attribute__((address_space(3))) unsigned int*)(l), 16, 0, 0)

#define MFMA16(a, b, c) __builtin_amdgcn_mfma_f32_16x16x32_bf16((a), (b), (c), 0, 0, 0)
#define SBAR() asm volatile("s_barrier" ::: "memory")

// split f32 [R,1024] -> bf16 [R,2048] = [hi | lo]
__global__ __launch_bounds__(256) void split_rows(const float* __restrict__ in,
                                                  u16* __restrict__ out) {
    int idx = blockIdx.x * 256 + threadIdx.x;
    int r = idx >> 8, s = idx & 255;
    float4 v = reinterpret_cast<const float4*>(in)[idx];
    ushort4 hi, lo;
    hi.x = f2bf(v.x); lo.x = f2bf(v.x - bf2f(hi.x));
    hi.y = f2bf(v.y); lo.y = f2bf(v.y - bf2f(hi.y));
    hi.z = f2bf(v.z); lo.z = f2bf(v.z - bf2f(hi.z));
    hi.w = f2bf(v.w); lo.w = f2bf(v.w - bf2f(hi.w));
    u16* row = out + (size_t)r * 2048;
    reinterpret_cast<ushort4*>(row)[s] = hi;
    reinterpret_cast<ushort4*>(row + 1024)[s] = lo;
}

// ============ 256x256 8-phase logits kernel (T1+T2+T3/T4+T5) ============
// C[4096,4096](f32) = A[4096,2048] x B'[4096,2048]^T, split-3 (K2=3072) with
// Hamilton perm/sign on B. 512 thr = 8 waves (2Mx4N), wave tile 128x64.
// LDS 128KB: 2 dbuf x (A[256][64] + B[256][64]) bf16, st-swizzled 16B blocks.
__global__ __launch_bounds__(512, 2) void logits8(
    const u16* __restrict__ A, const u16* __restrict__ B, const u16* __restrict__ Bneg,
    float* __restrict__ C, int perm_packed, int sign_packed)
{
    constexpr int NT = 48;                 // 3072 / 64
    __shared__ u16 L[2][2][256 * 64];      // [buf][A/B][row*64+col] = 128 KB
    const int tid = threadIdx.x;
    const int l = tid & 63, w = tid >> 6;
    const int wr = w >> 2, wc = w & 3;
    const int lr = l & 15, lh = l >> 4;
    // bijective XCD swizzle over 256 blocks: each XCD gets 2 full row-panels
    const int bid = (int)blockIdx.x;
    const int swz = (bid & 7) * 32 + (bid >> 3);
    const int row0 = (swz >> 4) * 256, col0 = (swz & 15) * 256;
    // stage lane mapping: linear LDS dest, pre-swizzled global source col
    const int srow = l >> 3;
    const int scol = ((l & 7) ^ (l >> 3)) * 8;

    f32x4 acc[8][4] = {};

    auto stage = [&](int t) {
        int k0 = t * 64;
        int sl = k0 >> 10, kk = k0 & 1023;
        int ch = kk >> 8;
        int p = (perm_packed >> (2 * ch)) & 3;
        const u16* Bsrc = ((sign_packed >> ch) & 1) ? Bneg : B;
        int kA = kk + (sl == 2 ? 1024 : 0);
        int kB = (sl == 1 ? 1024 : 0) + (p << 8) + (kk & 255);
        int bf = t & 1;
        #pragma unroll
        for (int i = 0; i < 4; ++i) {
            int r0 = w * 32 + i * 8;
            GLD16(&A[(size_t)(row0 + r0 + srow) * 2048 + kA + scol], &L[bf][0][r0 * 64]);
        }
        #pragma unroll
        for (int i = 0; i < 4; ++i) {
            int r0 = w * 32 + i * 8;
            GLD16(&Bsrc[(size_t)(col0 + r0 + srow) * 2048 + kB + scol], &L[bf][1][r0 * 64]);
        }
    };
    auto readA = [&](int bf, int m, int kh) -> short8 {
        int row = wr * 128 + m * 16 + lr;
        int c = ((kh * 4 + lh) ^ (lr & 7)) * 8;
        return *reinterpret_cast<const short8*>(&L[bf][0][row * 64 + c]);
    };
    auto readB = [&](int bf, int n, int kh) -> short8 {
        int row = wc * 64 + n * 16 + lr;
        int c = ((kh * 4 + lh) ^ (lr & 7)) * 8;
        return *reinterpret_cast<const short8*>(&L[bf][1][row * 64 + c]);
    };

    stage(0);
    stage(1);
    asm volatile("s_waitcnt vmcnt(8)" ::: "memory");
    SBAR();

    #pragma unroll 2
    for (int t = 0; t < NT; ++t) {
        const int bf = t & 1;
        short8 am[4][2], bn[4][2];
        // -------- phase 0: read A m0-3 + B n0-1; MFMA m0-3 x n0-1
        #pragma unroll
        for (int m = 0; m < 4; ++m) { am[m][0] = readA(bf, m, 0); am[m][1] = readA(bf, m, 1); }
        #pragma unroll
        for (int n = 0; n < 2; ++n) { bn[n][0] = readB(bf, n, 0); bn[n][1] = readB(bf, n, 1); }
        SBAR();
        __builtin_amdgcn_s_setprio(1);
        #pragma unroll
        for (int m = 0; m < 4; ++m)
            #pragma unroll
            for (int n = 0; n < 2; ++n) {
                acc[m][n] = MFMA16(am[m][0], bn[n][0], acc[m][n]);
                acc[m][n] = MFMA16(am[m][1], bn[n][1], acc[m][n]);
            }
        __builtin_amdgcn_s_setprio(0);
        SBAR();
        // -------- phase 1: read B n2-3; MFMA m0-3 x n2-3
        #pragma unroll
        for (int n = 2; n < 4; ++n) { bn[n][0] = readB(bf, n, 0); bn[n][1] = readB(bf, n, 1); }
        SBAR();
        __builtin_amdgcn_s_setprio(1);
        #pragma unroll
        for (int m = 0; m < 4; ++m)
            #pragma unroll
            for (int n = 2; n < 4; ++n) {
                acc[m][n] = MFMA16(am[m][0], bn[n][0], acc[m][n]);
                acc[m][n] = MFMA16(am[m][1], bn[n][1], acc[m][n]);
            }
        __builtin_amdgcn_s_setprio(0);
        SBAR();
        // -------- phase 2: read A m4-7 (reuse regs); MFMA m4-7 x n2-3
        #pragma unroll
        for (int m = 0; m < 4; ++m) { am[m][0] = readA(bf, 4 + m, 0); am[m][1] = readA(bf, 4 + m, 1); }
        SBAR();
        __builtin_amdgcn_s_setprio(1);
        #pragma unroll
        for (int m = 0; m < 4; ++m)
            #pragma unroll
            for (int n = 2; n < 4; ++n) {
                acc[4 + m][n] = MFMA16(am[m][0], bn[n][0], acc[4 + m][n]);
                acc[4 + m][n] = MFMA16(am[m][1], bn[n][1], acc[4 + m][n]);
            }
        __builtin_amdgcn_s_setprio(0);
        SBAR();
        // -------- phase 3: no LDS reads (bn held). Stage t+2 into this buf
        // (safe: all waves passed phase-2 barrier = done reading this buf).
        if (t + 2 < NT) stage(t + 2);
        SBAR();
        __builtin_amdgcn_s_setprio(1);
        #pragma unroll
        for (int m = 0; m < 4; ++m)
            #pragma unroll
            for (int n = 0; n < 2; ++n) {
                acc[4 + m][n] = MFMA16(am[m][0], bn[n][0], acc[4 + m][n]);
                acc[4 + m][n] = MFMA16(am[m][1], bn[n][1], acc[4 + m][n]);
            }
        __builtin_amdgcn_s_setprio(0);
        // counted wait: t+1's 8 loads retire, t+2's 8 stay in flight
        if (t + 2 < NT) { asm volatile("s_waitcnt vmcnt(8)" ::: "memory"); }
        else           { asm volatile("s_waitcnt vmcnt(0)" ::: "memory"); }
        SBAR();
    }

    #pragma unroll
    for (int m = 0; m < 8; ++m)
        #pragma unroll
        for (int n = 0; n < 4; ++n) {
            int gr = row0 + wr * 128 + m * 16 + lh * 4;
            int gc = col0 + wc * 64 + n * 16 + lr;
            #pragma unroll
            for (int j = 0; j < 4; ++j)
                C[(size_t)(gr + j) * 4096 + gc] = acc[m][n][j];
        }
}

// ============ general MFMA GEMM (QKV projections + PV) ============
// C = A * B^T. WR x WC wave grid (WR*WC = 4, 256 thr).
// SPLIT3: K2=3072 slices {A:hi,hi,lo}x{B:hi,lo,hi}. SA32: A f32 -> bf16 reg-stage.
// EPI: 0=f32 store; 1=split hi/lo bf16; 2=split + negated copy; 3=bf16 transposed.
template<int BM, int BN, int WR, int WC, bool SPLIT3, bool SA32, int EPI>
__global__ __launch_bounds__(256) void mfma_gemm(
    const void* __restrict__ Av, const u16* __restrict__ B,
    void* __restrict__ Cv, u16* __restrict__ C2,
    int K2, int lda, int ldb, int ldc)
{
    constexpr int WTM = BM / WR, WTN = BN / WC;
    constexpr int FM = WTM / 16, FN = WTN / 16;
    __shared__ u16 As[BM][64];
    __shared__ u16 Bs[BN][64];
    const int tid = threadIdx.x;
    const int l = tid & 63, w = tid >> 6;
    const int wr = w / WC, wc = w % WC;
    const int row0 = blockIdx.y * BM, col0 = blockIdx.x * BN;
    const int r8 = l >> 3;
    const int cb = (l & 7) * 8;
    const int lr = l & 15, lh = l >> 4;

    const u16* A = (const u16*)Av;
    const float* Af = (const float*)Av;

    f32x4 acc[FM][FN] = {};

    for (int k0 = 0; k0 < K2; k0 += 64) {
        int kA, kB;
        if (SPLIT3) {
            int sl = k0 >> 10;
            int kk = k0 & 1023;
            kA = kk + (sl == 2 ? 1024 : 0);
            kB = kk + (sl == 1 ? 1024 : 0);
        } else { kA = k0; kB = k0; }

        __syncthreads();
        if (SA32) {
            #pragma unroll
            for (int i = 0; i < BM / 16; ++i) {
                int idx = tid + i * 256;
                int r = idx >> 4, s4 = idx & 15;
                float4 v = *reinterpret_cast<const float4*>(
                    &Af[(size_t)(row0 + r) * lda + kA + s4 * 4]);
                ushort4 h;
                h.x = f2bf(v.x); h.y = f2bf(v.y); h.z = f2bf(v.z); h.w = f2bf(v.w);
                *reinterpret_cast<ushort4*>(&As[r][s4 * 4]) = h;
            }
        } else {
            #pragma unroll
            for (int i = 0; i < BM / 32; ++i) {
                int r0 = (w * (BM / 32) + i) * 8;
                GLD16(&A[(size_t)(row0 + r0 + r8) * lda + kA + cb], &As[r0][0]);
            }
        }
        #pragma unroll
        for (int i = 0; i < BN / 32; ++i) {
            int r0 = (w * (BN / 32) + i) * 8;
            GLD16(&B[(size_t)(col0 + r0 + r8) * ldb + kB + cb], &Bs[r0][0]);
        }
        __syncthreads();

        #pragma unroll
        for (int h = 0; h < 2; ++h) {
            short8 af[FM], bfr[FN];
            #pragma unroll
            for (int m = 0; m < FM; ++m)
                af[m] = *reinterpret_cast<const short8*>(
                    &As[wr * WTM + m * 16 + lr][h * 32 + lh * 8]);
            #pragma unroll
            for (int nn = 0; nn < FN; ++nn)
                bfr[nn] = *reinterpret_cast<const short8*>(
                    &Bs[wc * WTN + nn * 16 + lr][h * 32 + lh * 8]);
            #pragma unroll
            for (int m = 0; m < FM; ++m)
                #pragma unroll
                for (int nn = 0; nn < FN; ++nn)
                    acc[m][nn] = MFMA16(af[m], bfr[nn], acc[m][nn]);
        }
    }

    #pragma unroll
    for (int m = 0; m < FM; ++m) {
        #pragma unroll
        for (int nn = 0; nn < FN; ++nn) {
            int gr = row0 + wr * WTM + m * 16 + lh * 4;
            int gc = col0 + wc * WTN + nn * 16 + lr;
            f32x4 v = acc[m][nn];
            if (EPI == 0) {
                float* C = (float*)Cv;
                #pragma unroll
                for (int j = 0; j < 4; ++j)
                    C[(size_t)(gr + j) * ldc + gc] = v[j];
            } else if (EPI == 1 || EPI == 2) {
                u16* C = (u16*)Cv;
                #pragma unroll
                for (int j = 0; j < 4; ++j) {
                    u16 hi = f2bf(v[j]);
                    u16 lo = f2bf(v[j] - bf2f(hi));
                    size_t o = (size_t)(gr + j) * 2048 + gc;
                    C[o] = hi; C[o + 1024] = lo;
                    if (EPI == 2) { C2[o] = hi ^ 0x8000; C2[o + 1024] = lo ^ 0x8000; }
                }
            } else if (EPI == 3) {
                u16* C = (u16*)Cv;
                ushort4 o;
                o.x = f2bf(v[0]); o.y = f2bf(v[1]); o.z = f2bf(v[2]); o.w = f2bf(v[3]);
                *reinterpret_cast<ushort4*>(&C[(size_t)gc * 4096 + gr]) = o;
            }
        }
    }
}

// In-place row softmax over N=4096 columns; one 256-thr block per row.
__global__ __launch_bounds__(256) void softmax_rows(float* __restrict__ Wm, int N)
{
    const int tid = threadIdx.x;
    float* rp = Wm + (size_t)blockIdx.x * N;
    __shared__ float red[4];

    float4 v[4];
    float lmax = -INFINITY;
    #pragma unroll
    for (int l = 0; l < 4; ++l) {
        v[l] = *reinterpret_cast<const float4*>(&rp[(size_t)(l * 256 + tid) * 4]);
        lmax = fmaxf(lmax, fmaxf(fmaxf(v[l].x, v[l].y), fmaxf(v[l].z, v[l].w)));
    }
    #pragma unroll
    for (int off = 1; off < 64; off <<= 1)
        lmax = fmaxf(lmax, __shfl_xor(lmax, off, 64));
    if ((tid & 63) == 0) red[tid >> 6] = lmax;
    __syncthreads();
    const float m = fmaxf(fmaxf(red[0], red[1]), fmaxf(red[2], red[3]));
    __syncthreads();

    float ssum = 0.0f;
    #pragma unroll
    for (int l = 0; l < 4; ++l) {
        v[l].x = expf(v[l].x - m); v[l].y = expf(v[l].y - m);
        v[l].z = expf(v[l].z - m); v[l].w = expf(v[l].w - m);
        ssum += v[l].x + v[l].y + v[l].z + v[l].w;
    }
    #pragma unroll
    for (int off = 1; off < 64; off <<= 1)
        ssum += __shfl_xor(ssum, off, 64);
    if ((tid & 63) == 0) red[tid >> 6] = ssum;
    __syncthreads();
    const float inv = 1.0f / (red[0] + red[1] + red[2] + red[3]);

    #pragma unroll
    for (int l = 0; l < 4; ++l) {
        float4 o = make_float4(v[l].x * inv, v[l].y * inv, v[l].z * inv, v[l].w * inv);
        *reinterpret_cast<float4*>(&rp[(size_t)(l * 256 + tid) * 4]) = o;
    }
}

extern "C" void kernel_launch(void* const* d_in, const int* in_sizes, int n_in,
                              void* d_out, int out_size, void* d_ws, size_t ws_size,
                              hipStream_t stream)
{
    const int n = 4096, d = 1024;
    const float* x  = (const float*)d_in[0];
    const float* WQ = (const float*)d_in[1];
    const float* WK = (const float*)d_in[2];
    const float* WV = (const float*)d_in[3];

    float* y = (float*)d_out;                  // [4096,1024]
    float* w = y + (size_t)n * d;              // [4096,4096] logits/softmax (comp 3 = output)

    u16* xs  = (u16*)d_ws;                     // [4096,2048]
    u16* WQs = xs  + (size_t)n * 2048;         // [1024,2048]
    u16* WKs = WQs + (size_t)d * 2048;
    u16* WVs = WKs + (size_t)d * 2048;
    u16* Qs  = WVs + (size_t)d * 2048;         // [4096,2048]
    u16* Ks  = Qs  + (size_t)n * 2048;
    u16* Ksn = Ks  + (size_t)n * 2048;         // -Ks
    u16* Vt  = Ksn + (size_t)n * 2048;         // [1024,4096] bf16 V^T
    // total ws: 88.1 MB

    split_rows<<<n, 256, 0, stream>>>(x, xs);
    split_rows<<<d, 256, 0, stream>>>(WQ, WQs);
    split_rows<<<d, 256, 0, stream>>>(WK, WKs);
    split_rows<<<d, 256, 0, stream>>>(WV, WVs);

    // QKV projections: [4096,1024] = xs * Ws^T (split-bf16, K2=3072)
    dim3 blk(256);
    dim3 gq(d / 128, n / 128);
    mfma_gemm<128,128,2,2,true,false,1><<<gq, blk, 0, stream>>>(
        xs, WQs, Qs, nullptr, 3072, 2048, 2048, 0);
    mfma_gemm<128,128,2,2,true,false,2><<<gq, blk, 0, stream>>>(
        xs, WKs, Ks, Ksn, 3072, 2048, 2048, 0);
    mfma_gemm<128,128,2,2,true,false,3><<<gq, blk, 0, stream>>>(
        xs, WVs, Vt, nullptr, 3072, 2048, 2048, 0);

    // Hamilton tables: q-chunk t pairs k-chunk perm[t] with sign[t]
    const int permv[4] = {0xE4, 0xB1, 0x4E, 0x1B};
    const int signv[4] = {0x0E, 0x08, 0x02, 0x04};

    dim3 gpv(1, n / 64);
    for (int c = 0; c < 4; ++c) {
        logits8<<<256, 512, 0, stream>>>(Qs, Ks, Ksn, w, permv[c], signv[c]);
        softmax_rows<<<n, blk, 0, stream>>>(w, n);
        // PV: C[4096,256] = w[4096,4096] x Vt_chunk[256,4096]^T, BN=256 so w
        // is read exactly once; Vt chunk (2MB) stays L2-resident.
        mfma_gemm<64,256,1,4,false,true,0><<<gpv, blk, 0, stream>>>(
            w, Vt + (size_t)c * 256 * 4096, y + (size_t)c * 256, nullptr,
            4096, 4096, 4096, d);
    }
}

// Round 4
// 826.171 us; speedup vs baseline: 3.9141x; 1.3004x over previous
//
#include <hip/hip_runtime.h>
#include <cmath>

typedef __attribute__((ext_vector_type(8))) short short8;
typedef __attribute__((ext_vector_type(8))) _Float16 half8;
typedef __attribute__((ext_vector_type(4))) float f32x4;
typedef unsigned short u16;

__device__ __forceinline__ u16 f2bf(float f) {
    unsigned u = __float_as_uint(f);
    u = u + 0x7FFFu + ((u >> 16) & 1u);
    return (u16)(u >> 16);
}
__device__ __forceinline__ float bf2f(u16 b) {
    return __uint_as_float(((unsigned)b) << 16);
}
__device__ __forceinline__ u16 f2h(float f) {
    _Float16 h = (_Float16)f;
    return __builtin_bit_cast(u16, h);
}

#define GLD16(g, l)                                                              \
    __builtin_amdgcn_global_load_lds(                                            \
        (const __attribute__((address_space(1))) unsigned int*)(g),              \
        (__attribute__((address_space(3))) unsigned int*)(l), 16, 0, 0)

#define MFMA_BF(a, b, c) __builtin_amdgcn_mfma_f32_16x16x32_bf16((a), (b), (c), 0, 0, 0)
#define MFMA_F16(a, b, c)                                                        \
    __builtin_amdgcn_mfma_f32_16x16x32_f16(                                      \
        __builtin_bit_cast(half8, (a)), __builtin_bit_cast(half8, (b)), (c), 0, 0, 0)
#define SBAR() asm volatile("s_barrier" ::: "memory")

// split f32 [R,1024] -> bf16 [R,2048] = [hi | lo]
__global__ __launch_bounds__(256) void split_rows(const float* __restrict__ in,
                                                  u16* __restrict__ out) {
    int idx = blockIdx.x * 256 + threadIdx.x;
    int r = idx >> 8, s = idx & 255;
    float4 v = reinterpret_cast<const float4*>(in)[idx];
    ushort4 hi, lo;
    hi.x = f2bf(v.x); lo.x = f2bf(v.x - bf2f(hi.x));
    hi.y = f2bf(v.y); lo.y = f2bf(v.y - bf2f(hi.y));
    hi.z = f2bf(v.z); lo.z = f2bf(v.z - bf2f(hi.z));
    hi.w = f2bf(v.w); lo.w = f2bf(v.w - bf2f(hi.w));
    u16* row = out + (size_t)r * 2048;
    reinterpret_cast<ushort4*>(row)[s] = hi;
    reinterpret_cast<ushort4*>(row + 1024)[s] = lo;
}

// ============ 256x256 8-phase logits kernel, fp16, K=1024 ============
// C[4096,4096](f32) = Qh[4096,1024] x Kh'[4096,1024]^T with Hamilton
// per-256-chunk perm on Kh (sign via pre-negated copy). 512 thr = 8 waves
// (2Mx4N), wave tile 128x64. LDS 128KB: 2 dbuf x (A+B)[256][64] fp16,
// XOR-swizzled 16B blocks (swizzle applied on global source, linear LDS dest).
__global__ __launch_bounds__(512, 2) void logits8(
    const u16* __restrict__ A, const u16* __restrict__ B, const u16* __restrict__ Bneg,
    float* __restrict__ C, int perm_packed, int sign_packed)
{
    constexpr int NT = 16;                 // 1024 / 64
    __shared__ u16 L[2][2][256 * 64];      // [buf][A/B] = 128 KB
    const int tid = threadIdx.x;
    const int l = tid & 63, w = tid >> 6;
    const int wr = w >> 2, wc = w & 3;
    const int lr = l & 15, lh = l >> 4;
    // bijective XCD swizzle over 256 blocks: each XCD gets 2 full row-panels
    const int bid = (int)blockIdx.x;
    const int swz = (bid & 7) * 32 + (bid >> 3);
    const int row0 = (swz >> 4) * 256, col0 = (swz & 15) * 256;
    const int srow = l >> 3;
    const int scol = ((l & 7) ^ (l >> 3)) * 8;

    f32x4 acc[8][4] = {};

    auto stage = [&](int t) {
        int kA = t * 64;
        int ch = kA >> 8;
        int p = (perm_packed >> (2 * ch)) & 3;
        const u16* Bsrc = ((sign_packed >> ch) & 1) ? Bneg : B;
        int kB = (p << 8) + (kA & 255);
        int bf = t & 1;
        #pragma unroll
        for (int i = 0; i < 4; ++i) {
            int r0 = w * 32 + i * 8;
            GLD16(&A[(size_t)(row0 + r0 + srow) * 1024 + kA + scol], &L[bf][0][r0 * 64]);
        }
        #pragma unroll
        for (int i = 0; i < 4; ++i) {
            int r0 = w * 32 + i * 8;
            GLD16(&Bsrc[(size_t)(col0 + r0 + srow) * 1024 + kB + scol], &L[bf][1][r0 * 64]);
        }
    };
    auto readA = [&](int bf, int m, int kh) -> short8 {
        int row = wr * 128 + m * 16 + lr;
        int c = ((kh * 4 + lh) ^ (lr & 7)) * 8;
        return *reinterpret_cast<const short8*>(&L[bf][0][row * 64 + c]);
    };
    auto readB = [&](int bf, int n, int kh) -> short8 {
        int row = wc * 64 + n * 16 + lr;
        int c = ((kh * 4 + lh) ^ (lr & 7)) * 8;
        return *reinterpret_cast<const short8*>(&L[bf][1][row * 64 + c]);
    };

    stage(0);
    stage(1);
    asm volatile("s_waitcnt vmcnt(8)" ::: "memory");
    SBAR();

    #pragma unroll 2
    for (int t = 0; t < NT; ++t) {
        const int bf = t & 1;
        short8 am[4][2], bn[4][2];
        // phase 0: read A m0-3 + B n0-1; MFMA m0-3 x n0-1
        #pragma unroll
        for (int m = 0; m < 4; ++m) { am[m][0] = readA(bf, m, 0); am[m][1] = readA(bf, m, 1); }
        #pragma unroll
        for (int n = 0; n < 2; ++n) { bn[n][0] = readB(bf, n, 0); bn[n][1] = readB(bf, n, 1); }
        SBAR();
        __builtin_amdgcn_s_setprio(1);
        #pragma unroll
        for (int m = 0; m < 4; ++m)
            #pragma unroll
            for (int n = 0; n < 2; ++n) {
                acc[m][n] = MFMA_F16(am[m][0], bn[n][0], acc[m][n]);
                acc[m][n] = MFMA_F16(am[m][1], bn[n][1], acc[m][n]);
            }
        __builtin_amdgcn_s_setprio(0);
        SBAR();
        // phase 1: read B n2-3; MFMA m0-3 x n2-3
        #pragma unroll
        for (int n = 2; n < 4; ++n) { bn[n][0] = readB(bf, n, 0); bn[n][1] = readB(bf, n, 1); }
        SBAR();
        __builtin_amdgcn_s_setprio(1);
        #pragma unroll
        for (int m = 0; m < 4; ++m)
            #pragma unroll
            for (int n = 2; n < 4; ++n) {
                acc[m][n] = MFMA_F16(am[m][0], bn[n][0], acc[m][n]);
                acc[m][n] = MFMA_F16(am[m][1], bn[n][1], acc[m][n]);
            }
        __builtin_amdgcn_s_setprio(0);
        SBAR();
        // phase 2: read A m4-7; MFMA m4-7 x n2-3
        #pragma unroll
        for (int m = 0; m < 4; ++m) { am[m][0] = readA(bf, 4 + m, 0); am[m][1] = readA(bf, 4 + m, 1); }
        SBAR();
        __builtin_amdgcn_s_setprio(1);
        #pragma unroll
        for (int m = 0; m < 4; ++m)
            #pragma unroll
            for (int n = 2; n < 4; ++n) {
                acc[4 + m][n] = MFMA_F16(am[m][0], bn[n][0], acc[4 + m][n]);
                acc[4 + m][n] = MFMA_F16(am[m][1], bn[n][1], acc[4 + m][n]);
            }
        __builtin_amdgcn_s_setprio(0);
        SBAR();
        // phase 3: no LDS reads; stage t+2 into this buf (all waves past
        // phase-2 barrier = done reading it), then MFMA m4-7 x n0-1.
        if (t + 2 < NT) stage(t + 2);
        SBAR();
        __builtin_amdgcn_s_setprio(1);
        #pragma unroll
        for (int m = 0; m < 4; ++m)
            #pragma unroll
            for (int n = 0; n < 2; ++n) {
                acc[4 + m][n] = MFMA_F16(am[m][0], bn[n][0], acc[4 + m][n]);
                acc[4 + m][n] = MFMA_F16(am[m][1], bn[n][1], acc[4 + m][n]);
            }
        __builtin_amdgcn_s_setprio(0);
        if (t + 2 < NT) { asm volatile("s_waitcnt vmcnt(8)" ::: "memory"); }
        else           { asm volatile("s_waitcnt vmcnt(0)" ::: "memory"); }
        SBAR();
    }

    #pragma unroll
    for (int m = 0; m < 8; ++m)
        #pragma unroll
        for (int n = 0; n < 4; ++n) {
            int gr = row0 + wr * 128 + m * 16 + lh * 4;
            int gc = col0 + wc * 64 + n * 16 + lr;
            #pragma unroll
            for (int j = 0; j < 4; ++j)
                C[(size_t)(gr + j) * 4096 + gc] = acc[m][n][j];
        }
}

// ============ general MFMA GEMM (QKV projections + PV) ============
// C = A * B^T. WRxWC waves (256 thr). SPLIT3: K2=3072 bf16 slices
// {A:hi,hi,lo}x{B:hi,lo,hi}. SA32: A f32 -> fp16 reg-stage (PV path; LDS is
// then fp16). F16: B/LDS data fp16, use f16 MFMA.
// EPI: 0=f32 store; 1=fp16 store [*,1024]; 2=fp16 + negated copy -> C2;
//      3=fp16 transposed store (Vt[gc*4096+gr]).
template<int BM, int BN, int WR, int WC, bool SPLIT3, bool SA32, bool F16, int EPI>
__global__ __launch_bounds__(256) void mfma_gemm(
    const void* __restrict__ Av, const u16* __restrict__ B,
    void* __restrict__ Cv, u16* __restrict__ C2,
    int K2, int lda, int ldb, int ldc)
{
    constexpr int WTM = BM / WR, WTN = BN / WC;
    constexpr int FM = WTM / 16, FN = WTN / 16;
    __shared__ u16 As[BM][64];
    __shared__ u16 Bs[BN][64];
    const int tid = threadIdx.x;
    const int l = tid & 63, w = tid >> 6;
    const int wr = w / WC, wc = w % WC;
    const int row0 = blockIdx.y * BM, col0 = blockIdx.x * BN;
    const int r8 = l >> 3;
    const int cb = (l & 7) * 8;
    const int lr = l & 15, lh = l >> 4;

    const u16* A = (const u16*)Av;
    const float* Af = (const float*)Av;

    f32x4 acc[FM][FN] = {};

    for (int k0 = 0; k0 < K2; k0 += 64) {
        int kA, kB;
        if (SPLIT3) {
            int sl = k0 >> 10;
            int kk = k0 & 1023;
            kA = kk + (sl == 2 ? 1024 : 0);
            kB = kk + (sl == 1 ? 1024 : 0);
        } else { kA = k0; kB = k0; }

        __syncthreads();
        if (SA32) {
            #pragma unroll
            for (int i = 0; i < BM / 16; ++i) {
                int idx = tid + i * 256;
                int r = idx >> 4, s4 = idx & 15;
                float4 v = *reinterpret_cast<const float4*>(
                    &Af[(size_t)(row0 + r) * lda + kA + s4 * 4]);
                ushort4 h;
                h.x = f2h(v.x); h.y = f2h(v.y); h.z = f2h(v.z); h.w = f2h(v.w);
                *reinterpret_cast<ushort4*>(&As[r][s4 * 4]) = h;
            }
        } else {
            #pragma unroll
            for (int i = 0; i < BM / 32; ++i) {
                int r0 = (w * (BM / 32) + i) * 8;
                GLD16(&A[(size_t)(row0 + r0 + r8) * lda + kA + cb], &As[r0][0]);
            }
        }
        #pragma unroll
        for (int i = 0; i < BN / 32; ++i) {
            int r0 = (w * (BN / 32) + i) * 8;
            GLD16(&B[(size_t)(col0 + r0 + r8) * ldb + kB + cb], &Bs[r0][0]);
        }
        __syncthreads();

        #pragma unroll
        for (int h = 0; h < 2; ++h) {
            short8 af[FM], bfr[FN];
            #pragma unroll
            for (int m = 0; m < FM; ++m)
                af[m] = *reinterpret_cast<const short8*>(
                    &As[wr * WTM + m * 16 + lr][h * 32 + lh * 8]);
            #pragma unroll
            for (int nn = 0; nn < FN; ++nn)
                bfr[nn] = *reinterpret_cast<const short8*>(
                    &Bs[wc * WTN + nn * 16 + lr][h * 32 + lh * 8]);
            #pragma unroll
            for (int m = 0; m < FM; ++m)
                #pragma unroll
                for (int nn = 0; nn < FN; ++nn) {
                    if (F16) acc[m][nn] = MFMA_F16(af[m], bfr[nn], acc[m][nn]);
                    else     acc[m][nn] = MFMA_BF(af[m], bfr[nn], acc[m][nn]);
                }
        }
    }

    #pragma unroll
    for (int m = 0; m < FM; ++m) {
        #pragma unroll
        for (int nn = 0; nn < FN; ++nn) {
            int gr = row0 + wr * WTM + m * 16 + lh * 4;
            int gc = col0 + wc * WTN + nn * 16 + lr;
            f32x4 v = acc[m][nn];
            if (EPI == 0) {
                float* C = (float*)Cv;
                #pragma unroll
                for (int j = 0; j < 4; ++j)
                    C[(size_t)(gr + j) * ldc + gc] = v[j];
            } else if (EPI == 1 || EPI == 2) {
                u16* C = (u16*)Cv;
                #pragma unroll
                for (int j = 0; j < 4; ++j) {
                    u16 h = f2h(v[j]);
                    size_t o = (size_t)(gr + j) * 1024 + gc;
                    C[o] = h;
                    if (EPI == 2) C2[o] = h ^ 0x8000;
                }
            } else if (EPI == 3) {
                u16* C = (u16*)Cv;
                ushort4 o;
                o.x = f2h(v[0]); o.y = f2h(v[1]); o.z = f2h(v[2]); o.w = f2h(v[3]);
                *reinterpret_cast<ushort4*>(&C[(size_t)gc * 4096 + gr]) = o;
            }
        }
    }
}

// In-place row softmax over N=4096 columns; one 256-thr block per row.
__global__ __launch_bounds__(256) void softmax_rows(float* __restrict__ Wm, int N)
{
    const int tid = threadIdx.x;
    float* rp = Wm + (size_t)blockIdx.x * N;
    __shared__ float red[4];

    float4 v[4];
    float lmax = -INFINITY;
    #pragma unroll
    for (int l = 0; l < 4; ++l) {
        v[l] = *reinterpret_cast<const float4*>(&rp[(size_t)(l * 256 + tid) * 4]);
        lmax = fmaxf(lmax, fmaxf(fmaxf(v[l].x, v[l].y), fmaxf(v[l].z, v[l].w)));
    }
    #pragma unroll
    for (int off = 1; off < 64; off <<= 1)
        lmax = fmaxf(lmax, __shfl_xor(lmax, off, 64));
    if ((tid & 63) == 0) red[tid >> 6] = lmax;
    __syncthreads();
    const float m = fmaxf(fmaxf(red[0], red[1]), fmaxf(red[2], red[3]));
    __syncthreads();

    float ssum = 0.0f;
    #pragma unroll
    for (int l = 0; l < 4; ++l) {
        v[l].x = expf(v[l].x - m); v[l].y = expf(v[l].y - m);
        v[l].z = expf(v[l].z - m); v[l].w = expf(v[l].w - m);
        ssum += v[l].x + v[l].y + v[l].z + v[l].w;
    }
    #pragma unroll
    for (int off = 1; off < 64; off <<= 1)
        ssum += __shfl_xor(ssum, off, 64);
    if ((tid & 63) == 0) red[tid >> 6] = ssum;
    __syncthreads();
    const float inv = 1.0f / (red[0] + red[1] + red[2] + red[3]);

    #pragma unroll
    for (int l = 0; l < 4; ++l) {
        float4 o = make_float4(v[l].x * inv, v[l].y * inv, v[l].z * inv, v[l].w * inv);
        *reinterpret_cast<float4*>(&rp[(size_t)(l * 256 + tid) * 4]) = o;
    }
}

extern "C" void kernel_launch(void* const* d_in, const int* in_sizes, int n_in,
                              void* d_out, int out_size, void* d_ws, size_t ws_size,
                              hipStream_t stream)
{
    const int n = 4096, d = 1024;
    const float* x  = (const float*)d_in[0];
    const float* WQ = (const float*)d_in[1];
    const float* WK = (const float*)d_in[2];
    const float* WV = (const float*)d_in[3];

    float* y = (float*)d_out;                  // [4096,1024]
    float* w = y + (size_t)n * d;              // [4096,4096] logits/softmax (comp 3 = output)

    u16* xs  = (u16*)d_ws;                     // [4096,2048] bf16 hi|lo
    u16* WQs = xs  + (size_t)n * 2048;         // [1024,2048]
    u16* WKs = WQs + (size_t)d * 2048;
    u16* WVs = WKs + (size_t)d * 2048;
    u16* Qh  = WVs + (size_t)d * 2048;         // [4096,1024] fp16
    u16* Kh  = Qh  + (size_t)n * 1024;
    u16* Khn = Kh  + (size_t)n * 1024;         // -Kh
    u16* Vt  = Khn + (size_t)n * 1024;         // [1024,4096] fp16 V^T
    // total ws: ~63 MB

    split_rows<<<n, 256, 0, stream>>>(x, xs);
    split_rows<<<d, 256, 0, stream>>>(WQ, WQs);
    split_rows<<<d, 256, 0, stream>>>(WK, WKs);
    split_rows<<<d, 256, 0, stream>>>(WV, WVs);

    // QKV projections: split-bf16 (K2=3072) for accuracy, fp16 outputs.
    dim3 blk(256);
    dim3 gq(d / 128, n / 128);
    mfma_gemm<128,128,2,2,true,false,false,1><<<gq, blk, 0, stream>>>(
        xs, WQs, Qh, nullptr, 3072, 2048, 2048, 0);
    mfma_gemm<128,128,2,2,true,false,false,2><<<gq, blk, 0, stream>>>(
        xs, WKs, Kh, Khn, 3072, 2048, 2048, 0);
    mfma_gemm<128,128,2,2,true,false,false,3><<<gq, blk, 0, stream>>>(
        xs, WVs, Vt, nullptr, 3072, 2048, 2048, 0);

    // Hamilton tables: component c pairs Q-chunk a with K-chunk a^c
    const int permv[4] = {0xE4, 0xB1, 0x4E, 0x1B};
    const int signv[4] = {0x0E, 0x08, 0x02, 0x04};

    dim3 gpv(1, n / 64);
    for (int c = 0; c < 4; ++c) {
        logits8<<<256, 512, 0, stream>>>(Qh, Kh, Khn, w, permv[c], signv[c]);
        softmax_rows<<<n, blk, 0, stream>>>(w, n);
        // PV: C[4096,256] = w x Vt_chunk^T (fp16), w read once, Vt L2-resident
        mfma_gemm<64,256,1,4,false,true,true,0><<<gpv, blk, 0, stream>>>(
            w, Vt + (size_t)c * 256 * 4096, y + (size_t)c * 256, nullptr,
            4096, 4096, 4096, d);
    }
}

// Round 5
// 553.706 us; speedup vs baseline: 5.8401x; 1.4921x over previous
//
#include <hip/hip_runtime.h>
#include <cmath>

typedef __attribute__((ext_vector_type(8))) short short8;
typedef __attribute__((ext_vector_type(8))) _Float16 half8;
typedef __attribute__((ext_vector_type(4))) float f32x4;
typedef unsigned short u16;

__device__ __forceinline__ u16 f2bf(float f) {
    unsigned u = __float_as_uint(f);
    u = u + 0x7FFFu + ((u >> 16) & 1u);
    return (u16)(u >> 16);
}
__device__ __forceinline__ float bf2f(u16 b) {
    return __uint_as_float(((unsigned)b) << 16);
}
__device__ __forceinline__ u16 f2h(float f) {
    _Float16 h = (_Float16)f;
    return __builtin_bit_cast(u16, h);
}

#define GLD16(g, l)                                                              \
    __builtin_amdgcn_global_load_lds(                                            \
        (const __attribute__((address_space(1))) unsigned int*)(g),              \
        (__attribute__((address_space(3))) unsigned int*)(l), 16, 0, 0)

#define MFMA_BF(a, b, c) __builtin_amdgcn_mfma_f32_16x16x32_bf16((a), (b), (c), 0, 0, 0)
#define MFMA_F16(a, b, c)                                                        \
    __builtin_amdgcn_mfma_f32_16x16x32_f16(                                      \
        __builtin_bit_cast(half8, (a)), __builtin_bit_cast(half8, (b)), (c), 0, 0, 0)
#define SBAR() asm volatile("s_barrier" ::: "memory")

// split f32 [R,1024] -> bf16 [R,2048] = [hi | lo]
__global__ __launch_bounds__(256) void split_rows(const float* __restrict__ in,
                                                  u16* __restrict__ out) {
    int idx = blockIdx.x * 256 + threadIdx.x;
    int r = idx >> 8, s = idx & 255;
    float4 v = reinterpret_cast<const float4*>(in)[idx];
    ushort4 hi, lo;
    hi.x = f2bf(v.x); lo.x = f2bf(v.x - bf2f(hi.x));
    hi.y = f2bf(v.y); lo.y = f2bf(v.y - bf2f(hi.y));
    hi.z = f2bf(v.z); lo.z = f2bf(v.z - bf2f(hi.z));
    hi.w = f2bf(v.w); lo.w = f2bf(v.w - bf2f(hi.w));
    u16* row = out + (size_t)r * 2048;
    reinterpret_cast<ushort4*>(row)[s] = hi;
    reinterpret_cast<ushort4*>(row + 1024)[s] = lo;
}

// ============ 256x256 8-phase logits kernel, fp16, K=1024 ============
// C[4096,4096](f32) = Qh x Kh'^T (Hamilton perm on Kh cols; sign via Khn).
// Epilogue additionally writes per-(row, 256-col-tile) softmax partials:
// pm[row*16+tc] = rowmax, ps[row*16+tc] = sum(exp(l - rowmax)).
__global__ __launch_bounds__(512, 2) void logits8(
    const u16* __restrict__ A, const u16* __restrict__ B, const u16* __restrict__ Bneg,
    float* __restrict__ C, float* __restrict__ pm, float* __restrict__ ps,
    int perm_packed, int sign_packed)
{
    constexpr int NT = 16;                 // 1024 / 64
    __shared__ u16 L[2][2][256 * 64];      // [buf][A/B] = 128 KB
    const int tid = threadIdx.x;
    const int l = tid & 63, w = tid >> 6;
    const int wr = w >> 2, wc = w & 3;
    const int lr = l & 15, lh = l >> 4;
    const int bid = (int)blockIdx.x;
    const int swz = (bid & 7) * 32 + (bid >> 3);
    const int row0 = (swz >> 4) * 256, col0 = (swz & 15) * 256;
    const int tc = col0 >> 8;
    const int srow = l >> 3;
    const int scol = ((l & 7) ^ (l >> 3)) * 8;

    f32x4 acc[8][4] = {};

    auto stage = [&](int t) {
        int kA = t * 64;
        int ch = kA >> 8;
        int p = (perm_packed >> (2 * ch)) & 3;
        const u16* Bsrc = ((sign_packed >> ch) & 1) ? Bneg : B;
        int kB = (p << 8) + (kA & 255);
        int bf = t & 1;
        #pragma unroll
        for (int i = 0; i < 4; ++i) {
            int r0 = w * 32 + i * 8;
            GLD16(&A[(size_t)(row0 + r0 + srow) * 1024 + kA + scol], &L[bf][0][r0 * 64]);
        }
        #pragma unroll
        for (int i = 0; i < 4; ++i) {
            int r0 = w * 32 + i * 8;
            GLD16(&Bsrc[(size_t)(col0 + r0 + srow) * 1024 + kB + scol], &L[bf][1][r0 * 64]);
        }
    };
    auto readA = [&](int bf, int m, int kh) -> short8 {
        int row = wr * 128 + m * 16 + lr;
        int c = ((kh * 4 + lh) ^ (lr & 7)) * 8;
        return *reinterpret_cast<const short8*>(&L[bf][0][row * 64 + c]);
    };
    auto readB = [&](int bf, int n, int kh) -> short8 {
        int row = wc * 64 + n * 16 + lr;
        int c = ((kh * 4 + lh) ^ (lr & 7)) * 8;
        return *reinterpret_cast<const short8*>(&L[bf][1][row * 64 + c]);
    };

    stage(0);
    stage(1);
    asm volatile("s_waitcnt vmcnt(8)" ::: "memory");
    SBAR();

    #pragma unroll 2
    for (int t = 0; t < NT; ++t) {
        const int bf = t & 1;
        short8 am[4][2], bn[4][2];
        // phase 0
        #pragma unroll
        for (int m = 0; m < 4; ++m) { am[m][0] = readA(bf, m, 0); am[m][1] = readA(bf, m, 1); }
        #pragma unroll
        for (int n = 0; n < 2; ++n) { bn[n][0] = readB(bf, n, 0); bn[n][1] = readB(bf, n, 1); }
        SBAR();
        __builtin_amdgcn_s_setprio(1);
        #pragma unroll
        for (int m = 0; m < 4; ++m)
            #pragma unroll
            for (int n = 0; n < 2; ++n) {
                acc[m][n] = MFMA_F16(am[m][0], bn[n][0], acc[m][n]);
                acc[m][n] = MFMA_F16(am[m][1], bn[n][1], acc[m][n]);
            }
        __builtin_amdgcn_s_setprio(0);
        SBAR();
        // phase 1
        #pragma unroll
        for (int n = 2; n < 4; ++n) { bn[n][0] = readB(bf, n, 0); bn[n][1] = readB(bf, n, 1); }
        SBAR();
        __builtin_amdgcn_s_setprio(1);
        #pragma unroll
        for (int m = 0; m < 4; ++m)
            #pragma unroll
            for (int n = 2; n < 4; ++n) {
                acc[m][n] = MFMA_F16(am[m][0], bn[n][0], acc[m][n]);
                acc[m][n] = MFMA_F16(am[m][1], bn[n][1], acc[m][n]);
            }
        __builtin_amdgcn_s_setprio(0);
        SBAR();
        // phase 2
        #pragma unroll
        for (int m = 0; m < 4; ++m) { am[m][0] = readA(bf, 4 + m, 0); am[m][1] = readA(bf, 4 + m, 1); }
        SBAR();
        __builtin_amdgcn_s_setprio(1);
        #pragma unroll
        for (int m = 0; m < 4; ++m)
            #pragma unroll
            for (int n = 2; n < 4; ++n) {
                acc[4 + m][n] = MFMA_F16(am[m][0], bn[n][0], acc[4 + m][n]);
                acc[4 + m][n] = MFMA_F16(am[m][1], bn[n][1], acc[4 + m][n]);
            }
        __builtin_amdgcn_s_setprio(0);
        SBAR();
        // phase 3: stage t+2 into this buf, MFMA m4-7 x n0-1
        if (t + 2 < NT) stage(t + 2);
        SBAR();
        __builtin_amdgcn_s_setprio(1);
        #pragma unroll
        for (int m = 0; m < 4; ++m)
            #pragma unroll
            for (int n = 0; n < 2; ++n) {
                acc[4 + m][n] = MFMA_F16(am[m][0], bn[n][0], acc[4 + m][n]);
                acc[4 + m][n] = MFMA_F16(am[m][1], bn[n][1], acc[4 + m][n]);
            }
        __builtin_amdgcn_s_setprio(0);
        if (t + 2 < NT) { asm volatile("s_waitcnt vmcnt(8)" ::: "memory"); }
        else           { asm volatile("s_waitcnt vmcnt(0)" ::: "memory"); }
        SBAR();
    }

    // ---- stats epilogue: per-row (max, sumexp) over this block's 256 cols ----
    float* sc  = reinterpret_cast<float*>(&L[0][0][0]);   // [256][4] max partials
    float* sc2 = sc + 1024;                               // [256][4] sumexp partials
    __syncthreads();
    #pragma unroll
    for (int m = 0; m < 8; ++m)
        #pragma unroll
        for (int j = 0; j < 4; ++j) {
            float v = fmaxf(fmaxf(acc[m][0][j], acc[m][1][j]),
                            fmaxf(acc[m][2][j], acc[m][3][j]));
            #pragma unroll
            for (int off = 1; off < 16; off <<= 1) v = fmaxf(v, __shfl_xor(v, off, 16));
            if (lr == 0) sc[(wr * 128 + m * 16 + lh * 4 + j) * 4 + wc] = v;
        }
    __syncthreads();
    #pragma unroll
    for (int m = 0; m < 8; ++m)
        #pragma unroll
        for (int j = 0; j < 4; ++j) {
            int row = wr * 128 + m * 16 + lh * 4 + j;
            float M = fmaxf(fmaxf(sc[row * 4 + 0], sc[row * 4 + 1]),
                            fmaxf(sc[row * 4 + 2], sc[row * 4 + 3]));
            float s = expf(acc[m][0][j] - M) + expf(acc[m][1][j] - M)
                    + expf(acc[m][2][j] - M) + expf(acc[m][3][j] - M);
            #pragma unroll
            for (int off = 1; off < 16; off <<= 1) s += __shfl_xor(s, off, 16);
            if (lr == 0) sc2[row * 4 + wc] = s;
        }
    __syncthreads();
    if (wc == 0 && lr == 0) {
        #pragma unroll
        for (int m = 0; m < 8; ++m)
            #pragma unroll
            for (int j = 0; j < 4; ++j) {
                int row = wr * 128 + m * 16 + lh * 4 + j;
                float M = fmaxf(fmaxf(sc[row * 4 + 0], sc[row * 4 + 1]),
                                fmaxf(sc[row * 4 + 2], sc[row * 4 + 3]));
                float S = sc2[row * 4 + 0] + sc2[row * 4 + 1]
                        + sc2[row * 4 + 2] + sc2[row * 4 + 3];
                pm[(size_t)(row0 + row) * 16 + tc] = M;
                ps[(size_t)(row0 + row) * 16 + tc] = S;
            }
    }

    #pragma unroll
    for (int m = 0; m < 8; ++m)
        #pragma unroll
        for (int n = 0; n < 4; ++n) {
            int gr = row0 + wr * 128 + m * 16 + lh * 4;
            int gc = col0 + wc * 64 + n * 16 + lr;
            #pragma unroll
            for (int j = 0; j < 4; ++j)
                C[(size_t)(gr + j) * 4096 + gc] = acc[m][n][j];
        }
}

// ============ fused QKV projection ============
// C_all[4096,3072] = xs[4096,2048(hi|lo)] x Wall[3072,2048]^T, split-3 bf16.
// Epilogue by col0: [0,1024) -> Qh fp16; [1024,2048) -> Kh + Khn; [2048,3072)
// -> Vt fp16 transposed [1024][4096].
__global__ __launch_bounds__(256) void qkv_gemm(
    const u16* __restrict__ A, const u16* __restrict__ B,
    u16* __restrict__ Qh, u16* __restrict__ Kh, u16* __restrict__ Khn,
    u16* __restrict__ Vt)
{
    __shared__ u16 As[128][64];
    __shared__ u16 Bs[128][64];
    const int tid = threadIdx.x;
    const int l = tid & 63, w = tid >> 6;
    const int wr = w >> 1, wc = w & 1;
    const int row0 = blockIdx.y * 128, col0 = blockIdx.x * 128;
    const int r8 = l >> 3;
    const int cb = (l & 7) * 8;
    const int lr = l & 15, lh = l >> 4;

    f32x4 acc[4][4] = {};

    for (int k0 = 0; k0 < 3072; k0 += 64) {
        int sl = k0 >> 10;
        int kk = k0 & 1023;
        int kA = kk + (sl == 2 ? 1024 : 0);
        int kB = kk + (sl == 1 ? 1024 : 0);

        __syncthreads();
        #pragma unroll
        for (int i = 0; i < 4; ++i) {
            int r0 = (w * 4 + i) * 8;
            GLD16(&A[(size_t)(row0 + r0 + r8) * 2048 + kA + cb], &As[r0][0]);
        }
        #pragma unroll
        for (int i = 0; i < 4; ++i) {
            int r0 = (w * 4 + i) * 8;
            GLD16(&B[(size_t)(col0 + r0 + r8) * 2048 + kB + cb], &Bs[r0][0]);
        }
        __syncthreads();

        #pragma unroll
        for (int h = 0; h < 2; ++h) {
            short8 af[4], bfr[4];
            #pragma unroll
            for (int m = 0; m < 4; ++m)
                af[m] = *reinterpret_cast<const short8*>(
                    &As[wr * 64 + m * 16 + lr][h * 32 + lh * 8]);
            #pragma unroll
            for (int nn = 0; nn < 4; ++nn)
                bfr[nn] = *reinterpret_cast<const short8*>(
                    &Bs[wc * 64 + nn * 16 + lr][h * 32 + lh * 8]);
            #pragma unroll
            for (int m = 0; m < 4; ++m)
                #pragma unroll
                for (int nn = 0; nn < 4; ++nn)
                    acc[m][nn] = MFMA_BF(af[m], bfr[nn], acc[m][nn]);
        }
    }

    const int mode = col0 >> 10;   // 0=Q, 1=K, 2=V (block never straddles)
    #pragma unroll
    for (int m = 0; m < 4; ++m)
        #pragma unroll
        for (int nn = 0; nn < 4; ++nn) {
            int gr = row0 + wr * 64 + m * 16 + lh * 4;
            int gc = col0 + wc * 64 + nn * 16 + lr;
            int gcl = gc & 1023;
            f32x4 v = acc[m][nn];
            if (mode == 0) {
                #pragma unroll
                for (int j = 0; j < 4; ++j)
                    Qh[(size_t)(gr + j) * 1024 + gcl] = f2h(v[j]);
            } else if (mode == 1) {
                #pragma unroll
                for (int j = 0; j < 4; ++j) {
                    u16 h = f2h(v[j]);
                    size_t o = (size_t)(gr + j) * 1024 + gcl;
                    Kh[o] = h; Khn[o] = h ^ 0x8000;
                }
            } else {
                ushort4 o;
                o.x = f2h(v[0]); o.y = f2h(v[1]); o.z = f2h(v[2]); o.w = f2h(v[3]);
                *reinterpret_cast<ushort4*>(&Vt[(size_t)gcl * 4096 + gr]) = o;
            }
        }
}

// ============ fused softmax + PV ============
// Grid (4 k-chunks, 64 rowblocks), 256 thr = 4 waves (wave tile 64x64).
// Reads raw logits L (w buffer), normalizes with global row stats from pm/ps,
// multiplies by Vt chunk (fp16 MFMA), writes y-partials. WRITE_W: also writes
// normalized w in place (component 3 = required output).
template<bool WRITE_W>
__global__ __launch_bounds__(256) void pv_fused(
    const float* __restrict__ Lw, float* __restrict__ Wout,
    const u16* __restrict__ Vt, const float* __restrict__ pm,
    const float* __restrict__ ps, float* __restrict__ ypart, int c256)
{
    __shared__ u16 As[64 * 64];
    __shared__ u16 Bs[256 * 64];
    __shared__ float Ms[64], Is[64];
    const int tid = threadIdx.x;
    const int l = tid & 63, w = tid >> 6;
    const int lr = l & 15, lh = l >> 4;
    const int kc = blockIdx.x;
    const int row0 = blockIdx.y * 64;
    const int kbase = kc * 1024;
    const int srow = l >> 3, scol = ((l & 7) ^ (l >> 3)) * 8;

    if (tid < 64) {
        const float* pmr = &pm[(size_t)(row0 + tid) * 16];
        const float* psr = &ps[(size_t)(row0 + tid) * 16];
        float M = -INFINITY;
        #pragma unroll
        for (int i = 0; i < 16; ++i) M = fmaxf(M, pmr[i]);
        float S = 0.f;
        #pragma unroll
        for (int i = 0; i < 16; ++i) S += psr[i] * expf(pmr[i] - M);
        Ms[tid] = M; Is[tid] = 1.0f / S;
    }
    __syncthreads();

    float Mr[4], Ir[4];
    #pragma unroll
    for (int i = 0; i < 4; ++i) { int r = (tid >> 4) + i * 16; Mr[i] = Ms[r]; Ir[i] = Is[r]; }

    f32x4 acc[4][4] = {};

    for (int kt = 0; kt < 16; ++kt) {
        __syncthreads();
        // stage A: exp-normalize 64x64 f32 logits -> fp16, XOR-swizzled write
        #pragma unroll
        for (int i = 0; i < 4; ++i) {
            int idx = tid + i * 256;
            int r = idx >> 4, s4 = idx & 15;
            size_t ga = (size_t)(row0 + r) * 4096 + kbase + kt * 64 + s4 * 4;
            float4 v = *reinterpret_cast<const float4*>(&Lw[ga]);
            float e0 = expf(v.x - Mr[i]) * Ir[i];
            float e1 = expf(v.y - Mr[i]) * Ir[i];
            float e2 = expf(v.z - Mr[i]) * Ir[i];
            float e3 = expf(v.w - Mr[i]) * Ir[i];
            if (WRITE_W)
                *reinterpret_cast<float4*>(&Wout[ga]) = make_float4(e0, e1, e2, e3);
            ushort4 h;
            h.x = f2h(e0); h.y = f2h(e1); h.z = f2h(e2); h.w = f2h(e3);
            int dst = ((s4 >> 1) ^ (r & 7)) * 8 + (s4 & 1) * 4;
            *reinterpret_cast<ushort4*>(&As[r * 64 + dst]) = h;
        }
        // stage B: Vt rows c256..+256 x 64 k-cols (pre-swizzled source)
        #pragma unroll
        for (int i = 0; i < 8; ++i) {
            int r0 = w * 64 + i * 8;
            GLD16(&Vt[(size_t)(c256 + r0 + srow) * 4096 + kbase + kt * 64 + scol],
                  &Bs[r0 * 64]);
        }
        __syncthreads();
        #pragma unroll
        for (int kh = 0; kh < 2; ++kh) {
            short8 af[4], bfv[4];
            #pragma unroll
            for (int m = 0; m < 4; ++m)
                af[m] = *reinterpret_cast<const short8*>(
                    &As[(m * 16 + lr) * 64 + ((kh * 4 + lh) ^ (lr & 7)) * 8]);
            #pragma unroll
            for (int n = 0; n < 4; ++n)
                bfv[n] = *reinterpret_cast<const short8*>(
                    &Bs[(w * 64 + n * 16 + lr) * 64 + ((kh * 4 + lh) ^ (lr & 7)) * 8]);
            #pragma unroll
            for (int m = 0; m < 4; ++m)
                #pragma unroll
                for (int n = 0; n < 4; ++n)
                    acc[m][n] = MFMA_F16(af[m], bfv[n], acc[m][n]);
        }
    }

    #pragma unroll
    for (int m = 0; m < 4; ++m)
        #pragma unroll
        for (int n = 0; n < 4; ++n) {
            int rr = m * 16 + lh * 4;
            int col = w * 64 + n * 16 + lr;
            #pragma unroll
            for (int j = 0; j < 4; ++j)
                ypart[((size_t)kc * 4096 + row0 + rr + j) * 256 + col] = acc[m][n][j];
        }
}

// y[:, c256..c256+256] = sum over 4 k-chunk partials
__global__ __launch_bounds__(256) void reduce_y(const float* __restrict__ ypart,
                                                float* __restrict__ y, int c256)
{
    int idx = blockIdx.x * 256 + threadIdx.x;      // 262144 float4s
    int r = idx >> 6, c4 = (idx & 63) * 4;
    float4 s = *reinterpret_cast<const float4*>(&ypart[(size_t)r * 256 + c4]);
    #pragma unroll
    for (int kc = 1; kc < 4; ++kc) {
        float4 p = *reinterpret_cast<const float4*>(
            &ypart[((size_t)kc * 4096 + r) * 256 + c4]);
        s.x += p.x; s.y += p.y; s.z += p.z; s.w += p.w;
    }
    *reinterpret_cast<float4*>(&y[(size_t)r * 1024 + c256 + c4]) = s;
}

extern "C" void kernel_launch(void* const* d_in, const int* in_sizes, int n_in,
                              void* d_out, int out_size, void* d_ws, size_t ws_size,
                              hipStream_t stream)
{
    const int n = 4096, d = 1024;
    const float* x  = (const float*)d_in[0];
    const float* WQ = (const float*)d_in[1];
    const float* WK = (const float*)d_in[2];
    const float* WV = (const float*)d_in[3];

    float* y = (float*)d_out;                  // [4096,1024]
    float* w = y + (size_t)n * d;              // [4096,4096] raw logits / final w

    u16* xs   = (u16*)d_ws;                    // [4096,2048] bf16 hi|lo
    u16* WQs  = xs  + (size_t)n * 2048;        // [3072,2048] (Q,K,V contiguous)
    u16* WKs  = WQs + (size_t)d * 2048;
    u16* WVs  = WKs + (size_t)d * 2048;
    u16* Qh   = WVs + (size_t)d * 2048;        // [4096,1024] fp16
    u16* Kh   = Qh  + (size_t)n * 1024;
    u16* Khn  = Kh  + (size_t)n * 1024;
    u16* Vt   = Khn + (size_t)n * 1024;        // [1024,4096] fp16 V^T
    float* ypart = (float*)(Vt + (size_t)d * 4096);   // [4][4096][256] f32
    float* pm = ypart + (size_t)4 * n * 256;   // [4096][16]
    float* ps = pm + (size_t)n * 16;           // [4096][16]
    // total ws ~80.3 MB

    split_rows<<<n, 256, 0, stream>>>(x, xs);
    split_rows<<<d, 256, 0, stream>>>(WQ, WQs);
    split_rows<<<d, 256, 0, stream>>>(WK, WKs);
    split_rows<<<d, 256, 0, stream>>>(WV, WVs);

    qkv_gemm<<<dim3(24, 32), 256, 0, stream>>>(xs, WQs, Qh, Kh, Khn, Vt);

    const int permv[4] = {0xE4, 0xB1, 0x4E, 0x1B};
    const int signv[4] = {0x0E, 0x08, 0x02, 0x04};

    for (int c = 0; c < 4; ++c) {
        logits8<<<256, 512, 0, stream>>>(Qh, Kh, Khn, w, pm, ps, permv[c], signv[c]);
        if (c == 3)
            pv_fused<true><<<dim3(4, 64), 256, 0, stream>>>(w, w, Vt, pm, ps, ypart, c * 256);
        else
            pv_fused<false><<<dim3(4, 64), 256, 0, stream>>>(w, w, Vt, pm, ps, ypart, c * 256);
        reduce_y<<<1024, 256, 0, stream>>>(ypart, y, c * 256);
    }
}

// Round 6
// 460.028 us; speedup vs baseline: 7.0294x; 1.2036x over previous
//
#include <hip/hip_runtime.h>
#include <cmath>

typedef __attribute__((ext_vector_type(8))) short short8;
typedef __attribute__((ext_vector_type(8))) _Float16 half8;
typedef __attribute__((ext_vector_type(4))) float f32x4;
typedef unsigned short u16;

__device__ __forceinline__ u16 f2bf(float f) {
    unsigned u = __float_as_uint(f);
    u = u + 0x7FFFu + ((u >> 16) & 1u);
    return (u16)(u >> 16);
}
__device__ __forceinline__ float bf2f(u16 b) {
    return __uint_as_float(((unsigned)b) << 16);
}
__device__ __forceinline__ u16 f2h(float f) {
    _Float16 h = (_Float16)f;
    return __builtin_bit_cast(u16, h);
}
__device__ __forceinline__ float h2f(u16 b) {
    return (float)__builtin_bit_cast(_Float16, b);
}

#define GLD16(g, l)                                                              \
    __builtin_amdgcn_global_load_lds(                                            \
        (const __attribute__((address_space(1))) unsigned int*)(g),              \
        (__attribute__((address_space(3))) unsigned int*)(l), 16, 0, 0)

#define MFMA_BF(a, b, c) __builtin_amdgcn_mfma_f32_16x16x32_bf16((a), (b), (c), 0, 0, 0)
#define MFMA_F16(a, b, c)                                                        \
    __builtin_amdgcn_mfma_f32_16x16x32_f16(                                      \
        __builtin_bit_cast(half8, (a)), __builtin_bit_cast(half8, (b)), (c), 0, 0, 0)
#define SBAR() asm volatile("s_barrier" ::: "memory")

// split f32 [R,1024] -> bf16 [R,2048] = [hi | lo]
__global__ __launch_bounds__(256) void split_rows(const float* __restrict__ in,
                                                  u16* __restrict__ out) {
    int idx = blockIdx.x * 256 + threadIdx.x;
    int r = idx >> 8, s = idx & 255;
    float4 v = reinterpret_cast<const float4*>(in)[idx];
    ushort4 hi, lo;
    hi.x = f2bf(v.x); lo.x = f2bf(v.x - bf2f(hi.x));
    hi.y = f2bf(v.y); lo.y = f2bf(v.y - bf2f(hi.y));
    hi.z = f2bf(v.z); lo.z = f2bf(v.z - bf2f(hi.z));
    hi.w = f2bf(v.w); lo.w = f2bf(v.w - bf2f(hi.w));
    u16* row = out + (size_t)r * 2048;
    reinterpret_cast<ushort4*>(row)[s] = hi;
    reinterpret_cast<ushort4*>(row + 1024)[s] = lo;
}

// ============ 256x256 8-phase logits kernel, fp16, K=1024 ============
// C[4096,4096](f32) = Qh x Kh'^T (Hamilton perm on Kh cols; sign via Khn).
// Epilogue also writes per-(row, 256-col-tile) softmax partials pm/ps.
__global__ __launch_bounds__(512, 2) void logits8(
    const u16* __restrict__ A, const u16* __restrict__ B, const u16* __restrict__ Bneg,
    float* __restrict__ C, float* __restrict__ pm, float* __restrict__ ps,
    int perm_packed, int sign_packed)
{
    constexpr int NT = 16;
    __shared__ u16 L[2][2][256 * 64];
    const int tid = threadIdx.x;
    const int l = tid & 63, w = tid >> 6;
    const int wr = w >> 2, wc = w & 3;
    const int lr = l & 15, lh = l >> 4;
    const int bid = (int)blockIdx.x;
    const int swz = (bid & 7) * 32 + (bid >> 3);
    const int row0 = (swz >> 4) * 256, col0 = (swz & 15) * 256;
    const int tc = col0 >> 8;
    const int srow = l >> 3;
    const int scol = ((l & 7) ^ (l >> 3)) * 8;

    f32x4 acc[8][4] = {};

    auto stage = [&](int t) {
        int kA = t * 64;
        int ch = kA >> 8;
        int p = (perm_packed >> (2 * ch)) & 3;
        const u16* Bsrc = ((sign_packed >> ch) & 1) ? Bneg : B;
        int kB = (p << 8) + (kA & 255);
        int bf = t & 1;
        #pragma unroll
        for (int i = 0; i < 4; ++i) {
            int r0 = w * 32 + i * 8;
            GLD16(&A[(size_t)(row0 + r0 + srow) * 1024 + kA + scol], &L[bf][0][r0 * 64]);
        }
        #pragma unroll
        for (int i = 0; i < 4; ++i) {
            int r0 = w * 32 + i * 8;
            GLD16(&Bsrc[(size_t)(col0 + r0 + srow) * 1024 + kB + scol], &L[bf][1][r0 * 64]);
        }
    };
    auto readA = [&](int bf, int m, int kh) -> short8 {
        int row = wr * 128 + m * 16 + lr;
        int c = ((kh * 4 + lh) ^ (lr & 7)) * 8;
        return *reinterpret_cast<const short8*>(&L[bf][0][row * 64 + c]);
    };
    auto readB = [&](int bf, int n, int kh) -> short8 {
        int row = wc * 64 + n * 16 + lr;
        int c = ((kh * 4 + lh) ^ (lr & 7)) * 8;
        return *reinterpret_cast<const short8*>(&L[bf][1][row * 64 + c]);
    };

    stage(0);
    stage(1);
    asm volatile("s_waitcnt vmcnt(8)" ::: "memory");
    SBAR();

    #pragma unroll 2
    for (int t = 0; t < NT; ++t) {
        const int bf = t & 1;
        short8 am[4][2], bn[4][2];
        #pragma unroll
        for (int m = 0; m < 4; ++m) { am[m][0] = readA(bf, m, 0); am[m][1] = readA(bf, m, 1); }
        #pragma unroll
        for (int n = 0; n < 2; ++n) { bn[n][0] = readB(bf, n, 0); bn[n][1] = readB(bf, n, 1); }
        SBAR();
        __builtin_amdgcn_s_setprio(1);
        #pragma unroll
        for (int m = 0; m < 4; ++m)
            #pragma unroll
            for (int n = 0; n < 2; ++n) {
                acc[m][n] = MFMA_F16(am[m][0], bn[n][0], acc[m][n]);
                acc[m][n] = MFMA_F16(am[m][1], bn[n][1], acc[m][n]);
            }
        __builtin_amdgcn_s_setprio(0);
        SBAR();
        #pragma unroll
        for (int n = 2; n < 4; ++n) { bn[n][0] = readB(bf, n, 0); bn[n][1] = readB(bf, n, 1); }
        SBAR();
        __builtin_amdgcn_s_setprio(1);
        #pragma unroll
        for (int m = 0; m < 4; ++m)
            #pragma unroll
            for (int n = 2; n < 4; ++n) {
                acc[m][n] = MFMA_F16(am[m][0], bn[n][0], acc[m][n]);
                acc[m][n] = MFMA_F16(am[m][1], bn[n][1], acc[m][n]);
            }
        __builtin_amdgcn_s_setprio(0);
        SBAR();
        #pragma unroll
        for (int m = 0; m < 4; ++m) { am[m][0] = readA(bf, 4 + m, 0); am[m][1] = readA(bf, 4 + m, 1); }
        SBAR();
        __builtin_amdgcn_s_setprio(1);
        #pragma unroll
        for (int m = 0; m < 4; ++m)
            #pragma unroll
            for (int n = 2; n < 4; ++n) {
                acc[4 + m][n] = MFMA_F16(am[m][0], bn[n][0], acc[4 + m][n]);
                acc[4 + m][n] = MFMA_F16(am[m][1], bn[n][1], acc[4 + m][n]);
            }
        __builtin_amdgcn_s_setprio(0);
        SBAR();
        if (t + 2 < NT) stage(t + 2);
        SBAR();
        __builtin_amdgcn_s_setprio(1);
        #pragma unroll
        for (int m = 0; m < 4; ++m)
            #pragma unroll
            for (int n = 0; n < 2; ++n) {
                acc[4 + m][n] = MFMA_F16(am[m][0], bn[n][0], acc[4 + m][n]);
                acc[4 + m][n] = MFMA_F16(am[m][1], bn[n][1], acc[4 + m][n]);
            }
        __builtin_amdgcn_s_setprio(0);
        if (t + 2 < NT) { asm volatile("s_waitcnt vmcnt(8)" ::: "memory"); }
        else           { asm volatile("s_waitcnt vmcnt(0)" ::: "memory"); }
        SBAR();
    }

    // ---- stats epilogue ----
    float* sc  = reinterpret_cast<float*>(&L[0][0][0]);   // [256][4] max partials
    float* sc2 = sc + 1024;                               // [256][4] sumexp partials
    __syncthreads();
    #pragma unroll
    for (int m = 0; m < 8; ++m)
        #pragma unroll
        for (int j = 0; j < 4; ++j) {
            float v = fmaxf(fmaxf(acc[m][0][j], acc[m][1][j]),
                            fmaxf(acc[m][2][j], acc[m][3][j]));
            #pragma unroll
            for (int off = 1; off < 16; off <<= 1) v = fmaxf(v, __shfl_xor(v, off, 16));
            if (lr == 0) sc[(wr * 128 + m * 16 + lh * 4 + j) * 4 + wc] = v;
        }
    __syncthreads();
    #pragma unroll
    for (int m = 0; m < 8; ++m)
        #pragma unroll
        for (int j = 0; j < 4; ++j) {
            int row = wr * 128 + m * 16 + lh * 4 + j;
            float M = fmaxf(fmaxf(sc[row * 4 + 0], sc[row * 4 + 1]),
                            fmaxf(sc[row * 4 + 2], sc[row * 4 + 3]));
            float s = expf(acc[m][0][j] - M) + expf(acc[m][1][j] - M)
                    + expf(acc[m][2][j] - M) + expf(acc[m][3][j] - M);
            #pragma unroll
            for (int off = 1; off < 16; off <<= 1) s += __shfl_xor(s, off, 16);
            if (lr == 0) sc2[row * 4 + wc] = s;
        }
    __syncthreads();
    if (wc == 0 && lr == 0) {
        #pragma unroll
        for (int m = 0; m < 8; ++m)
            #pragma unroll
            for (int j = 0; j < 4; ++j) {
                int row = wr * 128 + m * 16 + lh * 4 + j;
                float M = fmaxf(fmaxf(sc[row * 4 + 0], sc[row * 4 + 1]),
                                fmaxf(sc[row * 4 + 2], sc[row * 4 + 3]));
                float S = sc2[row * 4 + 0] + sc2[row * 4 + 1]
                        + sc2[row * 4 + 2] + sc2[row * 4 + 3];
                pm[(size_t)(row0 + row) * 16 + tc] = M;
                ps[(size_t)(row0 + row) * 16 + tc] = S;
            }
    }

    #pragma unroll
    for (int m = 0; m < 8; ++m)
        #pragma unroll
        for (int n = 0; n < 4; ++n) {
            int gr = row0 + wr * 128 + m * 16 + lh * 4;
            int gc = col0 + wc * 64 + n * 16 + lr;
            #pragma unroll
            for (int j = 0; j < 4; ++j)
                C[(size_t)(gr + j) * 4096 + gc] = acc[m][n][j];
        }
}

// ============ fused QKV projection, 8-phase 256x256 ============
// Call[4096,3072] = xs[4096,2048(hi|lo)] x Wall[3072,2048]^T, split-3 bf16
// (K2=3072). Grid 192 blocks (16 row-panels x 12 col-panels), bijective XCD
// swizzle. Epilogue by col panel: Q -> Qh fp16; K -> Kh+Khn; V -> Vt^T fp16.
__global__ __launch_bounds__(512, 2) void qkv8(
    const u16* __restrict__ A, const u16* __restrict__ B,
    u16* __restrict__ Qh, u16* __restrict__ Kh, u16* __restrict__ Khn,
    u16* __restrict__ Vt)
{
    constexpr int NT = 48;                 // 3072 / 64
    __shared__ u16 L[2][2][256 * 64];
    const int tid = threadIdx.x;
    const int l = tid & 63, w = tid >> 6;
    const int wr = w >> 2, wc = w & 3;
    const int lr = l & 15, lh = l >> 4;
    // bijective XCD swizzle: 192 blocks, 24 per XCD
    const int bid = (int)blockIdx.x;
    const int wgid = (bid & 7) * 24 + (bid >> 3);
    const int row0 = (wgid / 12) * 256, col0 = (wgid % 12) * 256;
    const int srow = l >> 3;
    const int scol = ((l & 7) ^ (l >> 3)) * 8;

    f32x4 acc[8][4] = {};

    auto stage = [&](int t) {
        int k0 = t * 64;
        int sl = k0 >> 10, kk = k0 & 1023;
        int kA = kk + (sl == 2 ? 1024 : 0);
        int kB = kk + (sl == 1 ? 1024 : 0);
        int bf = t & 1;
        #pragma unroll
        for (int i = 0; i < 4; ++i) {
            int r0 = w * 32 + i * 8;
            GLD16(&A[(size_t)(row0 + r0 + srow) * 2048 + kA + scol], &L[bf][0][r0 * 64]);
        }
        #pragma unroll
        for (int i = 0; i < 4; ++i) {
            int r0 = w * 32 + i * 8;
            GLD16(&B[(size_t)(col0 + r0 + srow) * 2048 + kB + scol], &L[bf][1][r0 * 64]);
        }
    };
    auto readA = [&](int bf, int m, int kh) -> short8 {
        int row = wr * 128 + m * 16 + lr;
        int c = ((kh * 4 + lh) ^ (lr & 7)) * 8;
        return *reinterpret_cast<const short8*>(&L[bf][0][row * 64 + c]);
    };
    auto readB = [&](int bf, int n, int kh) -> short8 {
        int row = wc * 64 + n * 16 + lr;
        int c = ((kh * 4 + lh) ^ (lr & 7)) * 8;
        return *reinterpret_cast<const short8*>(&L[bf][1][row * 64 + c]);
    };

    stage(0);
    stage(1);
    asm volatile("s_waitcnt vmcnt(8)" ::: "memory");
    SBAR();

    #pragma unroll 2
    for (int t = 0; t < NT; ++t) {
        const int bf = t & 1;
        short8 am[4][2], bn[4][2];
        #pragma unroll
        for (int m = 0; m < 4; ++m) { am[m][0] = readA(bf, m, 0); am[m][1] = readA(bf, m, 1); }
        #pragma unroll
        for (int n = 0; n < 2; ++n) { bn[n][0] = readB(bf, n, 0); bn[n][1] = readB(bf, n, 1); }
        SBAR();
        __builtin_amdgcn_s_setprio(1);
        #pragma unroll
        for (int m = 0; m < 4; ++m)
            #pragma unroll
            for (int n = 0; n < 2; ++n) {
                acc[m][n] = MFMA_BF(am[m][0], bn[n][0], acc[m][n]);
                acc[m][n] = MFMA_BF(am[m][1], bn[n][1], acc[m][n]);
            }
        __builtin_amdgcn_s_setprio(0);
        SBAR();
        #pragma unroll
        for (int n = 2; n < 4; ++n) { bn[n][0] = readB(bf, n, 0); bn[n][1] = readB(bf, n, 1); }
        SBAR();
        __builtin_amdgcn_s_setprio(1);
        #pragma unroll
        for (int m = 0; m < 4; ++m)
            #pragma unroll
            for (int n = 2; n < 4; ++n) {
                acc[m][n] = MFMA_BF(am[m][0], bn[n][0], acc[m][n]);
                acc[m][n] = MFMA_BF(am[m][1], bn[n][1], acc[m][n]);
            }
        __builtin_amdgcn_s_setprio(0);
        SBAR();
        #pragma unroll
        for (int m = 0; m < 4; ++m) { am[m][0] = readA(bf, 4 + m, 0); am[m][1] = readA(bf, 4 + m, 1); }
        SBAR();
        __builtin_amdgcn_s_setprio(1);
        #pragma unroll
        for (int m = 0; m < 4; ++m)
            #pragma unroll
            for (int n = 2; n < 4; ++n) {
                acc[4 + m][n] = MFMA_BF(am[m][0], bn[n][0], acc[4 + m][n]);
                acc[4 + m][n] = MFMA_BF(am[m][1], bn[n][1], acc[4 + m][n]);
            }
        __builtin_amdgcn_s_setprio(0);
        SBAR();
        if (t + 2 < NT) stage(t + 2);
        SBAR();
        __builtin_amdgcn_s_setprio(1);
        #pragma unroll
        for (int m = 0; m < 4; ++m)
            #pragma unroll
            for (int n = 0; n < 2; ++n) {
                acc[4 + m][n] = MFMA_BF(am[m][0], bn[n][0], acc[4 + m][n]);
                acc[4 + m][n] = MFMA_BF(am[m][1], bn[n][1], acc[4 + m][n]);
            }
        __builtin_amdgcn_s_setprio(0);
        if (t + 2 < NT) { asm volatile("s_waitcnt vmcnt(8)" ::: "memory"); }
        else           { asm volatile("s_waitcnt vmcnt(0)" ::: "memory"); }
        SBAR();
    }

    const int mode = col0 >> 10;   // 0=Q, 1=K, 2=V (uniform per block)
    #pragma unroll
    for (int m = 0; m < 8; ++m)
        #pragma unroll
        for (int n = 0; n < 4; ++n) {
            int gr = row0 + wr * 128 + m * 16 + lh * 4;
            int gc = col0 + wc * 64 + n * 16 + lr;
            int gcl = gc & 1023;
            f32x4 v = acc[m][n];
            if (mode == 0) {
                #pragma unroll
                for (int j = 0; j < 4; ++j)
                    Qh[(size_t)(gr + j) * 1024 + gcl] = f2h(v[j]);
            } else if (mode == 1) {
                #pragma unroll
                for (int j = 0; j < 4; ++j) {
                    u16 h = f2h(v[j]);
                    size_t o = (size_t)(gr + j) * 1024 + gcl;
                    Kh[o] = h; Khn[o] = h ^ 0x8000;
                }
            } else {
                ushort4 o;
                o.x = f2h(v[0]); o.y = f2h(v[1]); o.z = f2h(v[2]); o.w = f2h(v[3]);
                *reinterpret_cast<ushort4*>(&Vt[(size_t)gcl * 4096 + gr]) = o;
            }
        }
}

// ============ fused softmax + PV, split-K 8 ============
// Grid (8 k-chunks of 512, 64 rowblocks) = 512 blocks, 256 thr = 4 waves.
// Normalizes raw logits with global stats, fp16 MFMA vs Vt, fp16 y-partials.
template<bool WRITE_W>
__global__ __launch_bounds__(256) void pv_fused(
    const float* __restrict__ Lw, float* __restrict__ Wout,
    const u16* __restrict__ Vt, const float* __restrict__ pm,
    const float* __restrict__ ps, u16* __restrict__ ypart, int c256)
{
    __shared__ u16 As[64 * 64];
    __shared__ u16 Bs[256 * 64];
    __shared__ float Ms[64], Is[64];
    const int tid = threadIdx.x;
    const int l = tid & 63, w = tid >> 6;
    const int lr = l & 15, lh = l >> 4;
    const int kc = blockIdx.x;
    const int row0 = blockIdx.y * 64;
    const int kbase = kc * 512;
    const int srow = l >> 3, scol = ((l & 7) ^ (l >> 3)) * 8;

    if (tid < 64) {
        const float* pmr = &pm[(size_t)(row0 + tid) * 16];
        const float* psr = &ps[(size_t)(row0 + tid) * 16];
        float M = -INFINITY;
        #pragma unroll
        for (int i = 0; i < 16; ++i) M = fmaxf(M, pmr[i]);
        float S = 0.f;
        #pragma unroll
        for (int i = 0; i < 16; ++i) S += psr[i] * expf(pmr[i] - M);
        Ms[tid] = M; Is[tid] = 1.0f / S;
    }
    __syncthreads();

    float Mr[4], Ir[4];
    #pragma unroll
    for (int i = 0; i < 4; ++i) { int r = (tid >> 4) + i * 16; Mr[i] = Ms[r]; Ir[i] = Is[r]; }

    f32x4 acc[4][4] = {};

    for (int kt = 0; kt < 8; ++kt) {
        __syncthreads();
        // stage A: exp-normalize 64x64 f32 logits -> fp16, XOR-swizzled write
        #pragma unroll
        for (int i = 0; i < 4; ++i) {
            int idx = tid + i * 256;
            int r = idx >> 4, s4 = idx & 15;
            size_t ga = (size_t)(row0 + r) * 4096 + kbase + kt * 64 + s4 * 4;
            float4 v = *reinterpret_cast<const float4*>(&Lw[ga]);
            float e0 = expf(v.x - Mr[i]) * Ir[i];
            float e1 = expf(v.y - Mr[i]) * Ir[i];
            float e2 = expf(v.z - Mr[i]) * Ir[i];
            float e3 = expf(v.w - Mr[i]) * Ir[i];
            if (WRITE_W)
                *reinterpret_cast<float4*>(&Wout[ga]) = make_float4(e0, e1, e2, e3);
            ushort4 h;
            h.x = f2h(e0); h.y = f2h(e1); h.z = f2h(e2); h.w = f2h(e3);
            int dst = ((s4 >> 1) ^ (r & 7)) * 8 + (s4 & 1) * 4;
            *reinterpret_cast<ushort4*>(&As[r * 64 + dst]) = h;
        }
        // stage B: Vt rows c256..+256 x 64 k-cols (pre-swizzled source)
        #pragma unroll
        for (int i = 0; i < 8; ++i) {
            int r0 = w * 64 + i * 8;
            GLD16(&Vt[(size_t)(c256 + r0 + srow) * 4096 + kbase + kt * 64 + scol],
                  &Bs[r0 * 64]);
        }
        __syncthreads();
        #pragma unroll
        for (int kh = 0; kh < 2; ++kh) {
            short8 af[4], bfv[4];
            #pragma unroll
            for (int m = 0; m < 4; ++m)
                af[m] = *reinterpret_cast<const short8*>(
                    &As[(m * 16 + lr) * 64 + ((kh * 4 + lh) ^ (lr & 7)) * 8]);
            #pragma unroll
            for (int n = 0; n < 4; ++n)
                bfv[n] = *reinterpret_cast<const short8*>(
                    &Bs[(w * 64 + n * 16 + lr) * 64 + ((kh * 4 + lh) ^ (lr & 7)) * 8]);
            #pragma unroll
            for (int m = 0; m < 4; ++m)
                #pragma unroll
                for (int n = 0; n < 4; ++n)
                    acc[m][n] = MFMA_F16(af[m], bfv[n], acc[m][n]);
        }
    }

    #pragma unroll
    for (int m = 0; m < 4; ++m)
        #pragma unroll
        for (int n = 0; n < 4; ++n) {
            int rr = m * 16 + lh * 4;
            int col = w * 64 + n * 16 + lr;
            #pragma unroll
            for (int j = 0; j < 4; ++j)
                ypart[((size_t)kc * 4096 + row0 + rr + j) * 256 + col] = f2h(acc[m][n][j]);
        }
}

// y[:, c256..c256+256] = sum over 8 k-chunk fp16 partials (f32 accumulate)
__global__ __launch_bounds__(256) void reduce_y(const u16* __restrict__ ypart,
                                                float* __restrict__ y, int c256)
{
    int idx = blockIdx.x * 256 + threadIdx.x;      // 262144 quads
    int r = idx >> 6, c4 = (idx & 63) * 4;
    float s0 = 0.f, s1 = 0.f, s2 = 0.f, s3 = 0.f;
    #pragma unroll
    for (int kc = 0; kc < 8; ++kc) {
        ushort4 p = *reinterpret_cast<const ushort4*>(
            &ypart[((size_t)kc * 4096 + r) * 256 + c4]);
        s0 += h2f(p.x); s1 += h2f(p.y); s2 += h2f(p.z); s3 += h2f(p.w);
    }
    *reinterpret_cast<float4*>(&y[(size_t)r * 1024 + c256 + c4]) =
        make_float4(s0, s1, s2, s3);
}

extern "C" void kernel_launch(void* const* d_in, const int* in_sizes, int n_in,
                              void* d_out, int out_size, void* d_ws, size_t ws_size,
                              hipStream_t stream)
{
    const int n = 4096, d = 1024;
    const float* x  = (const float*)d_in[0];
    const float* WQ = (const float*)d_in[1];
    const float* WK = (const float*)d_in[2];
    const float* WV = (const float*)d_in[3];

    float* y = (float*)d_out;                  // [4096,1024]
    float* w = y + (size_t)n * d;              // [4096,4096] raw logits / final w

    u16* xs   = (u16*)d_ws;                    // [4096,2048] bf16 hi|lo
    u16* WQs  = xs  + (size_t)n * 2048;        // [3072,2048] (Q,K,V contiguous)
    u16* WKs  = WQs + (size_t)d * 2048;
    u16* WVs  = WKs + (size_t)d * 2048;
    u16* Qh   = WVs + (size_t)d * 2048;        // [4096,1024] fp16
    u16* Kh   = Qh  + (size_t)n * 1024;
    u16* Khn  = Kh  + (size_t)n * 1024;
    u16* Vt   = Khn + (size_t)n * 1024;        // [1024,4096] fp16 V^T
    u16* ypart = Vt + (size_t)d * 4096;        // [8][4096][256] fp16 (16 MB)
    float* pm = (float*)(ypart + (size_t)8 * n * 256);   // [4096][16]
    float* ps = pm + (size_t)n * 16;           // [4096][16]
    // total ws ~80.3 MB

    split_rows<<<n, 256, 0, stream>>>(x, xs);
    split_rows<<<d, 256, 0, stream>>>(WQ, WQs);
    split_rows<<<d, 256, 0, stream>>>(WK, WKs);
    split_rows<<<d, 256, 0, stream>>>(WV, WVs);

    qkv8<<<192, 512, 0, stream>>>(xs, WQs, Qh, Kh, Khn, Vt);

    const int permv[4] = {0xE4, 0xB1, 0x4E, 0x1B};
    const int signv[4] = {0x0E, 0x08, 0x02, 0x04};

    for (int c = 0; c < 4; ++c) {
        logits8<<<256, 512, 0, stream>>>(Qh, Kh, Khn, w, pm, ps, permv[c], signv[c]);
        if (c == 3)
            pv_fused<true><<<dim3(8, 64), 256, 0, stream>>>(w, w, Vt, pm, ps, ypart, c * 256);
        else
            pv_fused<false><<<dim3(8, 64), 256, 0, stream>>>(w, w, Vt, pm, ps, ypart, c * 256);
        reduce_y<<<1024, 256, 0, stream>>>(ypart, y, c * 256);
    }
}

// Round 7
// 405.548 us; speedup vs baseline: 7.9737x; 1.1343x over previous
//
#include <hip/hip_runtime.h>
#include <cmath>

typedef __attribute__((ext_vector_type(8))) short short8;
typedef __attribute__((ext_vector_type(8))) _Float16 half8;
typedef __attribute__((ext_vector_type(4))) float f32x4;
typedef unsigned short u16;

__device__ __forceinline__ u16 f2h(float f) {
    _Float16 h = (_Float16)f;
    return __builtin_bit_cast(u16, h);
}
__device__ __forceinline__ float h2f(u16 b) {
    return (float)__builtin_bit_cast(_Float16, b);
}

#define GLD16(g, l)                                                              \
    __builtin_amdgcn_global_load_lds(                                            \
        (const __attribute__((address_space(1))) unsigned int*)(g),              \
        (__attribute__((address_space(3))) unsigned int*)(l), 16, 0, 0)

#define MFMA_F16(a, b, c)                                                        \
    __builtin_amdgcn_mfma_f32_16x16x32_f16(                                      \
        __builtin_bit_cast(half8, (a)), __builtin_bit_cast(half8, (b)), (c), 0, 0, 0)
#define SBAR() asm volatile("s_barrier" ::: "memory")

// f32 -> fp16 cast, one float4 per thread, grid covers tensor exactly
__global__ __launch_bounds__(256) void to_h(const float* __restrict__ in,
                                            u16* __restrict__ out) {
    int idx = blockIdx.x * 256 + threadIdx.x;
    float4 v = reinterpret_cast<const float4*>(in)[idx];
    ushort4 h;
    h.x = f2h(v.x); h.y = f2h(v.y); h.z = f2h(v.z); h.w = f2h(v.w);
    reinterpret_cast<ushort4*>(out)[idx] = h;
}

// ============ 256x256 8-phase logits kernel, fp16, K=1024 ============
// C[4096,4096](f32) = Qh x Kh'^T (Hamilton perm on Kh cols; sign via Khn).
// Epilogue also writes per-(row, 256-col-tile) softmax partials pm/ps.
__global__ __launch_bounds__(512, 2) void logits8(
    const u16* __restrict__ A, const u16* __restrict__ B, const u16* __restrict__ Bneg,
    float* __restrict__ C, float* __restrict__ pm, float* __restrict__ ps,
    int perm_packed, int sign_packed)
{
    constexpr int NT = 16;
    __shared__ u16 L[2][2][256 * 64];
    const int tid = threadIdx.x;
    const int l = tid & 63, w = tid >> 6;
    const int wr = w >> 2, wc = w & 3;
    const int lr = l & 15, lh = l >> 4;
    const int bid = (int)blockIdx.x;
    const int swz = (bid & 7) * 32 + (bid >> 3);
    const int row0 = (swz >> 4) * 256, col0 = (swz & 15) * 256;
    const int tc = col0 >> 8;
    const int srow = l >> 3;
    const int scol = ((l & 7) ^ (l >> 3)) * 8;

    f32x4 acc[8][4] = {};

    auto stage = [&](int t) {
        int kA = t * 64;
        int ch = kA >> 8;
        int p = (perm_packed >> (2 * ch)) & 3;
        const u16* Bsrc = ((sign_packed >> ch) & 1) ? Bneg : B;
        int kB = (p << 8) + (kA & 255);
        int bf = t & 1;
        #pragma unroll
        for (int i = 0; i < 4; ++i) {
            int r0 = w * 32 + i * 8;
            GLD16(&A[(size_t)(row0 + r0 + srow) * 1024 + kA + scol], &L[bf][0][r0 * 64]);
        }
        #pragma unroll
        for (int i = 0; i < 4; ++i) {
            int r0 = w * 32 + i * 8;
            GLD16(&Bsrc[(size_t)(col0 + r0 + srow) * 1024 + kB + scol], &L[bf][1][r0 * 64]);
        }
    };
    auto readA = [&](int bf, int m, int kh) -> short8 {
        int row = wr * 128 + m * 16 + lr;
        int c = ((kh * 4 + lh) ^ (lr & 7)) * 8;
        return *reinterpret_cast<const short8*>(&L[bf][0][row * 64 + c]);
    };
    auto readB = [&](int bf, int n, int kh) -> short8 {
        int row = wc * 64 + n * 16 + lr;
        int c = ((kh * 4 + lh) ^ (lr & 7)) * 8;
        return *reinterpret_cast<const short8*>(&L[bf][1][row * 64 + c]);
    };

    stage(0);
    stage(1);
    asm volatile("s_waitcnt vmcnt(8)" ::: "memory");
    SBAR();

    #pragma unroll 2
    for (int t = 0; t < NT; ++t) {
        const int bf = t & 1;
        short8 am[4][2], bn[4][2];
        #pragma unroll
        for (int m = 0; m < 4; ++m) { am[m][0] = readA(bf, m, 0); am[m][1] = readA(bf, m, 1); }
        #pragma unroll
        for (int n = 0; n < 2; ++n) { bn[n][0] = readB(bf, n, 0); bn[n][1] = readB(bf, n, 1); }
        SBAR();
        __builtin_amdgcn_s_setprio(1);
        #pragma unroll
        for (int m = 0; m < 4; ++m)
            #pragma unroll
            for (int n = 0; n < 2; ++n) {
                acc[m][n] = MFMA_F16(am[m][0], bn[n][0], acc[m][n]);
                acc[m][n] = MFMA_F16(am[m][1], bn[n][1], acc[m][n]);
            }
        __builtin_amdgcn_s_setprio(0);
        SBAR();
        #pragma unroll
        for (int n = 2; n < 4; ++n) { bn[n][0] = readB(bf, n, 0); bn[n][1] = readB(bf, n, 1); }
        SBAR();
        __builtin_amdgcn_s_setprio(1);
        #pragma unroll
        for (int m = 0; m < 4; ++m)
            #pragma unroll
            for (int n = 2; n < 4; ++n) {
                acc[m][n] = MFMA_F16(am[m][0], bn[n][0], acc[m][n]);
                acc[m][n] = MFMA_F16(am[m][1], bn[n][1], acc[m][n]);
            }
        __builtin_amdgcn_s_setprio(0);
        SBAR();
        #pragma unroll
        for (int m = 0; m < 4; ++m) { am[m][0] = readA(bf, 4 + m, 0); am[m][1] = readA(bf, 4 + m, 1); }
        SBAR();
        __builtin_amdgcn_s_setprio(1);
        #pragma unroll
        for (int m = 0; m < 4; ++m)
            #pragma unroll
            for (int n = 2; n < 4; ++n) {
                acc[4 + m][n] = MFMA_F16(am[m][0], bn[n][0], acc[4 + m][n]);
                acc[4 + m][n] = MFMA_F16(am[m][1], bn[n][1], acc[4 + m][n]);
            }
        __builtin_amdgcn_s_setprio(0);
        SBAR();
        if (t + 2 < NT) stage(t + 2);
        SBAR();
        __builtin_amdgcn_s_setprio(1);
        #pragma unroll
        for (int m = 0; m < 4; ++m)
            #pragma unroll
            for (int n = 0; n < 2; ++n) {
                acc[4 + m][n] = MFMA_F16(am[m][0], bn[n][0], acc[4 + m][n]);
                acc[4 + m][n] = MFMA_F16(am[m][1], bn[n][1], acc[4 + m][n]);
            }
        __builtin_amdgcn_s_setprio(0);
        if (t + 2 < NT) { asm volatile("s_waitcnt vmcnt(8)" ::: "memory"); }
        else           { asm volatile("s_waitcnt vmcnt(0)" ::: "memory"); }
        SBAR();
    }

    // ---- stats epilogue ----
    float* sc  = reinterpret_cast<float*>(&L[0][0][0]);   // [256][4] max partials
    float* sc2 = sc + 1024;                               // [256][4] sumexp partials
    __syncthreads();
    #pragma unroll
    for (int m = 0; m < 8; ++m)
        #pragma unroll
        for (int j = 0; j < 4; ++j) {
            float v = fmaxf(fmaxf(acc[m][0][j], acc[m][1][j]),
                            fmaxf(acc[m][2][j], acc[m][3][j]));
            #pragma unroll
            for (int off = 1; off < 16; off <<= 1) v = fmaxf(v, __shfl_xor(v, off, 16));
            if (lr == 0) sc[(wr * 128 + m * 16 + lh * 4 + j) * 4 + wc] = v;
        }
    __syncthreads();
    #pragma unroll
    for (int m = 0; m < 8; ++m)
        #pragma unroll
        for (int j = 0; j < 4; ++j) {
            int row = wr * 128 + m * 16 + lh * 4 + j;
            float M = fmaxf(fmaxf(sc[row * 4 + 0], sc[row * 4 + 1]),
                            fmaxf(sc[row * 4 + 2], sc[row * 4 + 3]));
            float s = expf(acc[m][0][j] - M) + expf(acc[m][1][j] - M)
                    + expf(acc[m][2][j] - M) + expf(acc[m][3][j] - M);
            #pragma unroll
            for (int off = 1; off < 16; off <<= 1) s += __shfl_xor(s, off, 16);
            if (lr == 0) sc2[row * 4 + wc] = s;
        }
    __syncthreads();
    if (wc == 0 && lr == 0) {
        #pragma unroll
        for (int m = 0; m < 8; ++m)
            #pragma unroll
            for (int j = 0; j < 4; ++j) {
                int row = wr * 128 + m * 16 + lh * 4 + j;
                float M = fmaxf(fmaxf(sc[row * 4 + 0], sc[row * 4 + 1]),
                                fmaxf(sc[row * 4 + 2], sc[row * 4 + 3]));
                float S = sc2[row * 4 + 0] + sc2[row * 4 + 1]
                        + sc2[row * 4 + 2] + sc2[row * 4 + 3];
                pm[(size_t)(row0 + row) * 16 + tc] = M;
                ps[(size_t)(row0 + row) * 16 + tc] = S;
            }
    }

    #pragma unroll
    for (int m = 0; m < 8; ++m)
        #pragma unroll
        for (int n = 0; n < 4; ++n) {
            int gr = row0 + wr * 128 + m * 16 + lh * 4;
            int gc = col0 + wc * 64 + n * 16 + lr;
            #pragma unroll
            for (int j = 0; j < 4; ++j)
                C[(size_t)(gr + j) * 4096 + gc] = acc[m][n][j];
        }
}

// ============ fused QKV projection, 8-phase 256x256, fp16 K=1024 ============
// Call[4096,3072] = xh[4096,1024] x Wh[3072,1024]^T (both fp16). Grid 192
// blocks (16 row-panels x 12 col-panels), bijective XCD swizzle. Epilogue by
// col panel: Q -> Qh; K -> Kh+Khn; V -> Vt^T.
__global__ __launch_bounds__(512, 2) void qkv8(
    const u16* __restrict__ A, const u16* __restrict__ B,
    u16* __restrict__ Qh, u16* __restrict__ Kh, u16* __restrict__ Khn,
    u16* __restrict__ Vt)
{
    constexpr int NT = 16;                 // 1024 / 64
    __shared__ u16 L[2][2][256 * 64];
    const int tid = threadIdx.x;
    const int l = tid & 63, w = tid >> 6;
    const int wr = w >> 2, wc = w & 3;
    const int lr = l & 15, lh = l >> 4;
    // bijective XCD swizzle: 192 blocks, 24 per XCD
    const int bid = (int)blockIdx.x;
    const int wgid = (bid & 7) * 24 + (bid >> 3);
    const int row0 = (wgid / 12) * 256, col0 = (wgid % 12) * 256;
    const int srow = l >> 3;
    const int scol = ((l & 7) ^ (l >> 3)) * 8;

    f32x4 acc[8][4] = {};

    auto stage = [&](int t) {
        int k0 = t * 64;
        int bf = t & 1;
        #pragma unroll
        for (int i = 0; i < 4; ++i) {
            int r0 = w * 32 + i * 8;
            GLD16(&A[(size_t)(row0 + r0 + srow) * 1024 + k0 + scol], &L[bf][0][r0 * 64]);
        }
        #pragma unroll
        for (int i = 0; i < 4; ++i) {
            int r0 = w * 32 + i * 8;
            GLD16(&B[(size_t)(col0 + r0 + srow) * 1024 + k0 + scol], &L[bf][1][r0 * 64]);
        }
    };
    auto readA = [&](int bf, int m, int kh) -> short8 {
        int row = wr * 128 + m * 16 + lr;
        int c = ((kh * 4 + lh) ^ (lr & 7)) * 8;
        return *reinterpret_cast<const short8*>(&L[bf][0][row * 64 + c]);
    };
    auto readB = [&](int bf, int n, int kh) -> short8 {
        int row = wc * 64 + n * 16 + lr;
        int c = ((kh * 4 + lh) ^ (lr & 7)) * 8;
        return *reinterpret_cast<const short8*>(&L[bf][1][row * 64 + c]);
    };

    stage(0);
    stage(1);
    asm volatile("s_waitcnt vmcnt(8)" ::: "memory");
    SBAR();

    #pragma unroll 2
    for (int t = 0; t < NT; ++t) {
        const int bf = t & 1;
        short8 am[4][2], bn[4][2];
        #pragma unroll
        for (int m = 0; m < 4; ++m) { am[m][0] = readA(bf, m, 0); am[m][1] = readA(bf, m, 1); }
        #pragma unroll
        for (int n = 0; n < 2; ++n) { bn[n][0] = readB(bf, n, 0); bn[n][1] = readB(bf, n, 1); }
        SBAR();
        __builtin_amdgcn_s_setprio(1);
        #pragma unroll
        for (int m = 0; m < 4; ++m)
            #pragma unroll
            for (int n = 0; n < 2; ++n) {
                acc[m][n] = MFMA_F16(am[m][0], bn[n][0], acc[m][n]);
                acc[m][n] = MFMA_F16(am[m][1], bn[n][1], acc[m][n]);
            }
        __builtin_amdgcn_s_setprio(0);
        SBAR();
        #pragma unroll
        for (int n = 2; n < 4; ++n) { bn[n][0] = readB(bf, n, 0); bn[n][1] = readB(bf, n, 1); }
        SBAR();
        __builtin_amdgcn_s_setprio(1);
        #pragma unroll
        for (int m = 0; m < 4; ++m)
            #pragma unroll
            for (int n = 2; n < 4; ++n) {
                acc[m][n] = MFMA_F16(am[m][0], bn[n][0], acc[m][n]);
                acc[m][n] = MFMA_F16(am[m][1], bn[n][1], acc[m][n]);
            }
        __builtin_amdgcn_s_setprio(0);
        SBAR();
        #pragma unroll
        for (int m = 0; m < 4; ++m) { am[m][0] = readA(bf, 4 + m, 0); am[m][1] = readA(bf, 4 + m, 1); }
        SBAR();
        __builtin_amdgcn_s_setprio(1);
        #pragma unroll
        for (int m = 0; m < 4; ++m)
            #pragma unroll
            for (int n = 2; n < 4; ++n) {
                acc[4 + m][n] = MFMA_F16(am[m][0], bn[n][0], acc[4 + m][n]);
                acc[4 + m][n] = MFMA_F16(am[m][1], bn[n][1], acc[4 + m][n]);
            }
        __builtin_amdgcn_s_setprio(0);
        SBAR();
        if (t + 2 < NT) stage(t + 2);
        SBAR();
        __builtin_amdgcn_s_setprio(1);
        #pragma unroll
        for (int m = 0; m < 4; ++m)
            #pragma unroll
            for (int n = 0; n < 2; ++n) {
                acc[4 + m][n] = MFMA_F16(am[m][0], bn[n][0], acc[4 + m][n]);
                acc[4 + m][n] = MFMA_F16(am[m][1], bn[n][1], acc[4 + m][n]);
            }
        __builtin_amdgcn_s_setprio(0);
        if (t + 2 < NT) { asm volatile("s_waitcnt vmcnt(8)" ::: "memory"); }
        else           { asm volatile("s_waitcnt vmcnt(0)" ::: "memory"); }
        SBAR();
    }

    const int mode = col0 >> 10;   // 0=Q, 1=K, 2=V (uniform per block)
    #pragma unroll
    for (int m = 0; m < 8; ++m)
        #pragma unroll
        for (int n = 0; n < 4; ++n) {
            int gr = row0 + wr * 128 + m * 16 + lh * 4;
            int gc = col0 + wc * 64 + n * 16 + lr;
            int gcl = gc & 1023;
            f32x4 v = acc[m][n];
            if (mode == 0) {
                #pragma unroll
                for (int j = 0; j < 4; ++j)
                    Qh[(size_t)(gr + j) * 1024 + gcl] = f2h(v[j]);
            } else if (mode == 1) {
                #pragma unroll
                for (int j = 0; j < 4; ++j) {
                    u16 h = f2h(v[j]);
                    size_t o = (size_t)(gr + j) * 1024 + gcl;
                    Kh[o] = h; Khn[o] = h ^ 0x8000;
                }
            } else {
                ushort4 o;
                o.x = f2h(v[0]); o.y = f2h(v[1]); o.z = f2h(v[2]); o.w = f2h(v[3]);
                *reinterpret_cast<ushort4*>(&Vt[(size_t)gcl * 4096 + gr]) = o;
            }
        }
}

// ============ fused softmax + PV, split-K 8 ============
// Grid (8 k-chunks of 512, 64 rowblocks) = 512 blocks, 256 thr = 4 waves.
// Normalizes raw logits with global stats, fp16 MFMA vs Vt, fp16 y-partials.
template<bool WRITE_W>
__global__ __launch_bounds__(256) void pv_fused(
    const float* __restrict__ Lw, float* __restrict__ Wout,
    const u16* __restrict__ Vt, const float* __restrict__ pm,
    const float* __restrict__ ps, u16* __restrict__ ypart, int c256)
{
    __shared__ u16 As[64 * 64];
    __shared__ u16 Bs[256 * 64];
    __shared__ float Ms[64], Is[64];
    const int tid = threadIdx.x;
    const int l = tid & 63, w = tid >> 6;
    const int lr = l & 15, lh = l >> 4;
    const int kc = blockIdx.x;
    const int row0 = blockIdx.y * 64;
    const int kbase = kc * 512;
    const int srow = l >> 3, scol = ((l & 7) ^ (l >> 3)) * 8;

    if (tid < 64) {
        const float* pmr = &pm[(size_t)(row0 + tid) * 16];
        const float* psr = &ps[(size_t)(row0 + tid) * 16];
        float M = -INFINITY;
        #pragma unroll
        for (int i = 0; i < 16; ++i) M = fmaxf(M, pmr[i]);
        float S = 0.f;
        #pragma unroll
        for (int i = 0; i < 16; ++i) S += psr[i] * expf(pmr[i] - M);
        Ms[tid] = M; Is[tid] = 1.0f / S;
    }
    __syncthreads();

    float Mr[4], Ir[4];
    #pragma unroll
    for (int i = 0; i < 4; ++i) { int r = (tid >> 4) + i * 16; Mr[i] = Ms[r]; Ir[i] = Is[r]; }

    f32x4 acc[4][4] = {};

    for (int kt = 0; kt < 8; ++kt) {
        __syncthreads();
        // stage A: exp-normalize 64x64 f32 logits -> fp16, XOR-swizzled write
        #pragma unroll
        for (int i = 0; i < 4; ++i) {
            int idx = tid + i * 256;
            int r = idx >> 4, s4 = idx & 15;
            size_t ga = (size_t)(row0 + r) * 4096 + kbase + kt * 64 + s4 * 4;
            float4 v = *reinterpret_cast<const float4*>(&Lw[ga]);
            float e0 = expf(v.x - Mr[i]) * Ir[i];
            float e1 = expf(v.y - Mr[i]) * Ir[i];
            float e2 = expf(v.z - Mr[i]) * Ir[i];
            float e3 = expf(v.w - Mr[i]) * Ir[i];
            if (WRITE_W)
                *reinterpret_cast<float4*>(&Wout[ga]) = make_float4(e0, e1, e2, e3);
            ushort4 h;
            h.x = f2h(e0); h.y = f2h(e1); h.z = f2h(e2); h.w = f2h(e3);
            int dst = ((s4 >> 1) ^ (r & 7)) * 8 + (s4 & 1) * 4;
            *reinterpret_cast<ushort4*>(&As[r * 64 + dst]) = h;
        }
        // stage B: Vt rows c256..+256 x 64 k-cols (pre-swizzled source)
        #pragma unroll
        for (int i = 0; i < 8; ++i) {
            int r0 = w * 64 + i * 8;
            GLD16(&Vt[(size_t)(c256 + r0 + srow) * 4096 + kbase + kt * 64 + scol],
                  &Bs[r0 * 64]);
        }
        __syncthreads();
        #pragma unroll
        for (int kh = 0; kh < 2; ++kh) {
            short8 af[4], bfv[4];
            #pragma unroll
            for (int m = 0; m < 4; ++m)
                af[m] = *reinterpret_cast<const short8*>(
                    &As[(m * 16 + lr) * 64 + ((kh * 4 + lh) ^ (lr & 7)) * 8]);
            #pragma unroll
            for (int n = 0; n < 4; ++n)
                bfv[n] = *reinterpret_cast<const short8*>(
                    &Bs[(w * 64 + n * 16 + lr) * 64 + ((kh * 4 + lh) ^ (lr & 7)) * 8]);
            #pragma unroll
            for (int m = 0; m < 4; ++m)
                #pragma unroll
                for (int n = 0; n < 4; ++n)
                    acc[m][n] = MFMA_F16(af[m], bfv[n], acc[m][n]);
        }
    }

    #pragma unroll
    for (int m = 0; m < 4; ++m)
        #pragma unroll
        for (int n = 0; n < 4; ++n) {
            int rr = m * 16 + lh * 4;
            int col = w * 64 + n * 16 + lr;
            #pragma unroll
            for (int j = 0; j < 4; ++j)
                ypart[((size_t)kc * 4096 + row0 + rr + j) * 256 + col] = f2h(acc[m][n][j]);
        }
}

// y[:, c256..c256+256] = sum over 8 k-chunk fp16 partials (f32 accumulate)
__global__ __launch_bounds__(256) void reduce_y(const u16* __restrict__ ypart,
                                                float* __restrict__ y, int c256)
{
    int idx = blockIdx.x * 256 + threadIdx.x;      // 262144 quads
    int r = idx >> 6, c4 = (idx & 63) * 4;
    float s0 = 0.f, s1 = 0.f, s2 = 0.f, s3 = 0.f;
    #pragma unroll
    for (int kc = 0; kc < 8; ++kc) {
        ushort4 p = *reinterpret_cast<const ushort4*>(
            &ypart[((size_t)kc * 4096 + r) * 256 + c4]);
        s0 += h2f(p.x); s1 += h2f(p.y); s2 += h2f(p.z); s3 += h2f(p.w);
    }
    *reinterpret_cast<float4*>(&y[(size_t)r * 1024 + c256 + c4]) =
        make_float4(s0, s1, s2, s3);
}

extern "C" void kernel_launch(void* const* d_in, const int* in_sizes, int n_in,
                              void* d_out, int out_size, void* d_ws, size_t ws_size,
                              hipStream_t stream)
{
    const int n = 4096, d = 1024;
    const float* x  = (const float*)d_in[0];
    const float* WQ = (const float*)d_in[1];
    const float* WK = (const float*)d_in[2];
    const float* WV = (const float*)d_in[3];

    float* y = (float*)d_out;                  // [4096,1024]
    float* w = y + (size_t)n * d;              // [4096,4096] raw logits / final w

    u16* xh   = (u16*)d_ws;                    // [4096,1024] fp16
    u16* Wh   = xh  + (size_t)n * 1024;        // [3072,1024] fp16 (WQ,WK,WV)
    u16* Qh   = Wh  + (size_t)3 * d * 1024;    // [4096,1024] fp16
    u16* Kh   = Qh  + (size_t)n * 1024;
    u16* Khn  = Kh  + (size_t)n * 1024;
    u16* Vt   = Khn + (size_t)n * 1024;        // [1024,4096] fp16 V^T
    u16* ypart = Vt + (size_t)d * 4096;        // [8][4096][256] fp16 (16 MB)
    float* pm = (float*)(ypart + (size_t)8 * n * 256);   // [4096][16]
    float* ps = pm + (size_t)n * 16;           // [4096][16]
    // total ws ~66 MB

    to_h<<<n * d / 1024, 256, 0, stream>>>(x, xh);
    to_h<<<d * d / 1024, 256, 0, stream>>>(WQ, Wh);
    to_h<<<d * d / 1024, 256, 0, stream>>>(WK, Wh + (size_t)d * 1024);
    to_h<<<d * d / 1024, 256, 0, stream>>>(WV, Wh + (size_t)2 * d * 1024);

    qkv8<<<192, 512, 0, stream>>>(xh, Wh, Qh, Kh, Khn, Vt);

    const int permv[4] = {0xE4, 0xB1, 0x4E, 0x1B};
    const int signv[4] = {0x0E, 0x08, 0x02, 0x04};

    for (int c = 0; c < 4; ++c) {
        logits8<<<256, 512, 0, stream>>>(Qh, Kh, Khn, w, pm, ps, permv[c], signv[c]);
        if (c == 3)
            pv_fused<true><<<dim3(8, 64), 256, 0, stream>>>(w, w, Vt, pm, ps, ypart, c * 256);
        else
            pv_fused<false><<<dim3(8, 64), 256, 0, stream>>>(w, w, Vt, pm, ps, ypart, c * 256);
        reduce_y<<<1024, 256, 0, stream>>>(ypart, y, c * 256);
    }
}

// Round 8
// 374.261 us; speedup vs baseline: 8.6403x; 1.0836x over previous
//
#include <hip/hip_runtime.h>
#include <cmath>

typedef __attribute__((ext_vector_type(8))) short short8;
typedef __attribute__((ext_vector_type(8))) _Float16 half8;
typedef __attribute__((ext_vector_type(4))) float f32x4;
typedef unsigned short u16;

__device__ __forceinline__ u16 f2h(float f) {
    _Float16 h = (_Float16)f;
    return __builtin_bit_cast(u16, h);
}
__device__ __forceinline__ float h2f(u16 b) {
    return (float)__builtin_bit_cast(_Float16, b);
}

#define GLD16(g, l)                                                              \
    __builtin_amdgcn_global_load_lds(                                            \
        (const __attribute__((address_space(1))) unsigned int*)(g),              \
        (__attribute__((address_space(3))) unsigned int*)(l), 16, 0, 0)

#define MFMA_F16(a, b, c)                                                        \
    __builtin_amdgcn_mfma_f32_16x16x32_f16(                                      \
        __builtin_bit_cast(half8, (a)), __builtin_bit_cast(half8, (b)), (c), 0, 0, 0)
#define SBAR() asm volatile("s_barrier" ::: "memory")

// f32 -> fp16 cast, one float4 per thread, grid covers tensor exactly
__global__ __launch_bounds__(256) void to_h(const float* __restrict__ in,
                                            u16* __restrict__ out) {
    int idx = blockIdx.x * 256 + threadIdx.x;
    float4 v = reinterpret_cast<const float4*>(in)[idx];
    ushort4 h;
    h.x = f2h(v.x); h.y = f2h(v.y); h.z = f2h(v.z); h.w = f2h(v.w);
    reinterpret_cast<ushort4*>(out)[idx] = h;
}

// ============ 256x256 8-phase logits kernel, fp16, K=1024 ============
// Computes S = Qh x Kh'^T (Hamilton perm on Kh cols; sign via Khn).
// Epilogue (barrier-free): per-wave 64-col stats pm/ps[row*64+tcol] =
// (rowmax, sumexp), and stores D = S - rowmax(tile) as fp16 into Ch.
__global__ __launch_bounds__(512, 2) void logits8(
    const u16* __restrict__ A, const u16* __restrict__ B, const u16* __restrict__ Bneg,
    u16* __restrict__ Ch, float* __restrict__ pm, float* __restrict__ ps,
    int perm_packed, int sign_packed)
{
    constexpr int NT = 16;
    __shared__ u16 L[2][2][256 * 64];
    const int tid = threadIdx.x;
    const int l = tid & 63, w = tid >> 6;
    const int wr = w >> 2, wc = w & 3;
    const int lr = l & 15, lh = l >> 4;
    const int bid = (int)blockIdx.x;
    const int swz = (bid & 7) * 32 + (bid >> 3);
    const int row0 = (swz >> 4) * 256, col0 = (swz & 15) * 256;
    const int srow = l >> 3;
    const int scol = ((l & 7) ^ (l >> 3)) * 8;

    f32x4 acc[8][4] = {};

    auto stage = [&](int t) {
        int kA = t * 64;
        int ch = kA >> 8;
        int p = (perm_packed >> (2 * ch)) & 3;
        const u16* Bsrc = ((sign_packed >> ch) & 1) ? Bneg : B;
        int kB = (p << 8) + (kA & 255);
        int bf = t & 1;
        #pragma unroll
        for (int i = 0; i < 4; ++i) {
            int r0 = w * 32 + i * 8;
            GLD16(&A[(size_t)(row0 + r0 + srow) * 1024 + kA + scol], &L[bf][0][r0 * 64]);
        }
        #pragma unroll
        for (int i = 0; i < 4; ++i) {
            int r0 = w * 32 + i * 8;
            GLD16(&Bsrc[(size_t)(col0 + r0 + srow) * 1024 + kB + scol], &L[bf][1][r0 * 64]);
        }
    };
    auto readA = [&](int bf, int m, int kh) -> short8 {
        int row = wr * 128 + m * 16 + lr;
        int c = ((kh * 4 + lh) ^ (lr & 7)) * 8;
        return *reinterpret_cast<const short8*>(&L[bf][0][row * 64 + c]);
    };
    auto readB = [&](int bf, int n, int kh) -> short8 {
        int row = wc * 64 + n * 16 + lr;
        int c = ((kh * 4 + lh) ^ (lr & 7)) * 8;
        return *reinterpret_cast<const short8*>(&L[bf][1][row * 64 + c]);
    };

    stage(0);
    stage(1);
    asm volatile("s_waitcnt vmcnt(8)" ::: "memory");
    SBAR();

    #pragma unroll 2
    for (int t = 0; t < NT; ++t) {
        const int bf = t & 1;
        short8 am[4][2], bn[4][2];
        #pragma unroll
        for (int m = 0; m < 4; ++m) { am[m][0] = readA(bf, m, 0); am[m][1] = readA(bf, m, 1); }
        #pragma unroll
        for (int n = 0; n < 2; ++n) { bn[n][0] = readB(bf, n, 0); bn[n][1] = readB(bf, n, 1); }
        SBAR();
        __builtin_amdgcn_s_setprio(1);
        #pragma unroll
        for (int m = 0; m < 4; ++m)
            #pragma unroll
            for (int n = 0; n < 2; ++n) {
                acc[m][n] = MFMA_F16(am[m][0], bn[n][0], acc[m][n]);
                acc[m][n] = MFMA_F16(am[m][1], bn[n][1], acc[m][n]);
            }
        __builtin_amdgcn_s_setprio(0);
        SBAR();
        #pragma unroll
        for (int n = 2; n < 4; ++n) { bn[n][0] = readB(bf, n, 0); bn[n][1] = readB(bf, n, 1); }
        SBAR();
        __builtin_amdgcn_s_setprio(1);
        #pragma unroll
        for (int m = 0; m < 4; ++m)
            #pragma unroll
            for (int n = 2; n < 4; ++n) {
                acc[m][n] = MFMA_F16(am[m][0], bn[n][0], acc[m][n]);
                acc[m][n] = MFMA_F16(am[m][1], bn[n][1], acc[m][n]);
            }
        __builtin_amdgcn_s_setprio(0);
        SBAR();
        #pragma unroll
        for (int m = 0; m < 4; ++m) { am[m][0] = readA(bf, 4 + m, 0); am[m][1] = readA(bf, 4 + m, 1); }
        SBAR();
        __builtin_amdgcn_s_setprio(1);
        #pragma unroll
        for (int m = 0; m < 4; ++m)
            #pragma unroll
            for (int n = 2; n < 4; ++n) {
                acc[4 + m][n] = MFMA_F16(am[m][0], bn[n][0], acc[4 + m][n]);
                acc[4 + m][n] = MFMA_F16(am[m][1], bn[n][1], acc[4 + m][n]);
            }
        __builtin_amdgcn_s_setprio(0);
        SBAR();
        if (t + 2 < NT) stage(t + 2);
        SBAR();
        __builtin_amdgcn_s_setprio(1);
        #pragma unroll
        for (int m = 0; m < 4; ++m)
            #pragma unroll
            for (int n = 0; n < 2; ++n) {
                acc[4 + m][n] = MFMA_F16(am[m][0], bn[n][0], acc[4 + m][n]);
                acc[4 + m][n] = MFMA_F16(am[m][1], bn[n][1], acc[4 + m][n]);
            }
        __builtin_amdgcn_s_setprio(0);
        if (t + 2 < NT) { asm volatile("s_waitcnt vmcnt(8)" ::: "memory"); }
        else           { asm volatile("s_waitcnt vmcnt(0)" ::: "memory"); }
        SBAR();
    }

    // ---- barrier-free fused stats + fp16 D-store epilogue ----
    // Each wave owns 64 cols: stats tile = 64 cols, tcol in [0,64).
    const int tcol = (col0 >> 6) + wc;
    #pragma unroll
    for (int m = 0; m < 8; ++m) {
        #pragma unroll
        for (int j = 0; j < 4; ++j) {
            int row = row0 + wr * 128 + m * 16 + lh * 4 + j;
            float v = fmaxf(fmaxf(acc[m][0][j], acc[m][1][j]),
                            fmaxf(acc[m][2][j], acc[m][3][j]));
            #pragma unroll
            for (int off = 1; off < 16; off <<= 1) v = fmaxf(v, __shfl_xor(v, off, 16));
            float s = expf(acc[m][0][j] - v) + expf(acc[m][1][j] - v)
                    + expf(acc[m][2][j] - v) + expf(acc[m][3][j] - v);
            #pragma unroll
            for (int off = 1; off < 16; off <<= 1) s += __shfl_xor(s, off, 16);
            if (lr == 0) {
                pm[(size_t)row * 64 + tcol] = v;
                ps[(size_t)row * 64 + tcol] = s;
            }
            #pragma unroll
            for (int n = 0; n < 4; ++n) {
                int gc = col0 + wc * 64 + n * 16 + lr;
                Ch[(size_t)row * 4096 + gc] = f2h(acc[m][n][j] - v);
            }
        }
    }
}

// ============ fused QKV projection, 8-phase 256x256, fp16 K=1024 ============
__global__ __launch_bounds__(512, 2) void qkv8(
    const u16* __restrict__ A, const u16* __restrict__ B,
    u16* __restrict__ Qh, u16* __restrict__ Kh, u16* __restrict__ Khn,
    u16* __restrict__ Vt)
{
    constexpr int NT = 16;                 // 1024 / 64
    __shared__ u16 L[2][2][256 * 64];
    const int tid = threadIdx.x;
    const int l = tid & 63, w = tid >> 6;
    const int wr = w >> 2, wc = w & 3;
    const int lr = l & 15, lh = l >> 4;
    const int bid = (int)blockIdx.x;
    const int wgid = (bid & 7) * 24 + (bid >> 3);
    const int row0 = (wgid / 12) * 256, col0 = (wgid % 12) * 256;
    const int srow = l >> 3;
    const int scol = ((l & 7) ^ (l >> 3)) * 8;

    f32x4 acc[8][4] = {};

    auto stage = [&](int t) {
        int k0 = t * 64;
        int bf = t & 1;
        #pragma unroll
        for (int i = 0; i < 4; ++i) {
            int r0 = w * 32 + i * 8;
            GLD16(&A[(size_t)(row0 + r0 + srow) * 1024 + k0 + scol], &L[bf][0][r0 * 64]);
        }
        #pragma unroll
        for (int i = 0; i < 4; ++i) {
            int r0 = w * 32 + i * 8;
            GLD16(&B[(size_t)(col0 + r0 + srow) * 1024 + k0 + scol], &L[bf][1][r0 * 64]);
        }
    };
    auto readA = [&](int bf, int m, int kh) -> short8 {
        int row = wr * 128 + m * 16 + lr;
        int c = ((kh * 4 + lh) ^ (lr & 7)) * 8;
        return *reinterpret_cast<const short8*>(&L[bf][0][row * 64 + c]);
    };
    auto readB = [&](int bf, int n, int kh) -> short8 {
        int row = wc * 64 + n * 16 + lr;
        int c = ((kh * 4 + lh) ^ (lr & 7)) * 8;
        return *reinterpret_cast<const short8*>(&L[bf][1][row * 64 + c]);
    };

    stage(0);
    stage(1);
    asm volatile("s_waitcnt vmcnt(8)" ::: "memory");
    SBAR();

    #pragma unroll 2
    for (int t = 0; t < NT; ++t) {
        const int bf = t & 1;
        short8 am[4][2], bn[4][2];
        #pragma unroll
        for (int m = 0; m < 4; ++m) { am[m][0] = readA(bf, m, 0); am[m][1] = readA(bf, m, 1); }
        #pragma unroll
        for (int n = 0; n < 2; ++n) { bn[n][0] = readB(bf, n, 0); bn[n][1] = readB(bf, n, 1); }
        SBAR();
        __builtin_amdgcn_s_setprio(1);
        #pragma unroll
        for (int m = 0; m < 4; ++m)
            #pragma unroll
            for (int n = 0; n < 2; ++n) {
                acc[m][n] = MFMA_F16(am[m][0], bn[n][0], acc[m][n]);
                acc[m][n] = MFMA_F16(am[m][1], bn[n][1], acc[m][n]);
            }
        __builtin_amdgcn_s_setprio(0);
        SBAR();
        #pragma unroll
        for (int n = 2; n < 4; ++n) { bn[n][0] = readB(bf, n, 0); bn[n][1] = readB(bf, n, 1); }
        SBAR();
        __builtin_amdgcn_s_setprio(1);
        #pragma unroll
        for (int m = 0; m < 4; ++m)
            #pragma unroll
            for (int n = 2; n < 4; ++n) {
                acc[m][n] = MFMA_F16(am[m][0], bn[n][0], acc[m][n]);
                acc[m][n] = MFMA_F16(am[m][1], bn[n][1], acc[m][n]);
            }
        __builtin_amdgcn_s_setprio(0);
        SBAR();
        #pragma unroll
        for (int m = 0; m < 4; ++m) { am[m][0] = readA(bf, 4 + m, 0); am[m][1] = readA(bf, 4 + m, 1); }
        SBAR();
        __builtin_amdgcn_s_setprio(1);
        #pragma unroll
        for (int m = 0; m < 4; ++m)
            #pragma unroll
            for (int n = 2; n < 4; ++n) {
                acc[4 + m][n] = MFMA_F16(am[m][0], bn[n][0], acc[4 + m][n]);
                acc[4 + m][n] = MFMA_F16(am[m][1], bn[n][1], acc[4 + m][n]);
            }
        __builtin_amdgcn_s_setprio(0);
        SBAR();
        if (t + 2 < NT) stage(t + 2);
        SBAR();
        __builtin_amdgcn_s_setprio(1);
        #pragma unroll
        for (int m = 0; m < 4; ++m)
            #pragma unroll
            for (int n = 0; n < 2; ++n) {
                acc[4 + m][n] = MFMA_F16(am[m][0], bn[n][0], acc[4 + m][n]);
                acc[4 + m][n] = MFMA_F16(am[m][1], bn[n][1], acc[4 + m][n]);
            }
        __builtin_amdgcn_s_setprio(0);
        if (t + 2 < NT) { asm volatile("s_waitcnt vmcnt(8)" ::: "memory"); }
        else           { asm volatile("s_waitcnt vmcnt(0)" ::: "memory"); }
        SBAR();
    }

    const int mode = col0 >> 10;   // 0=Q, 1=K, 2=V (uniform per block)
    #pragma unroll
    for (int m = 0; m < 8; ++m)
        #pragma unroll
        for (int n = 0; n < 4; ++n) {
            int gr = row0 + wr * 128 + m * 16 + lh * 4;
            int gc = col0 + wc * 64 + n * 16 + lr;
            int gcl = gc & 1023;
            f32x4 v = acc[m][n];
            if (mode == 0) {
                #pragma unroll
                for (int j = 0; j < 4; ++j)
                    Qh[(size_t)(gr + j) * 1024 + gcl] = f2h(v[j]);
            } else if (mode == 1) {
                #pragma unroll
                for (int j = 0; j < 4; ++j) {
                    u16 h = f2h(v[j]);
                    size_t o = (size_t)(gr + j) * 1024 + gcl;
                    Kh[o] = h; Khn[o] = h ^ 0x8000;
                }
            } else {
                ushort4 o;
                o.x = f2h(v[0]); o.y = f2h(v[1]); o.z = f2h(v[2]); o.w = f2h(v[3]);
                *reinterpret_cast<ushort4*>(&Vt[(size_t)gcl * 4096 + gr]) = o;
            }
        }
}

// ============ fused softmax + PV, split-K 8, fp16 D-logits ============
// Reads Lh = fp16(l - M_tile), reconstructs w = exp(D + M_t - M)/S with
// global row stats combined from pm/ps[row][64], fp16 MFMA vs Vt.
template<bool WRITE_W>
__global__ __launch_bounds__(256) void pv_fused(
    const u16* __restrict__ Lh, float* __restrict__ Wout,
    const u16* __restrict__ Vt, const float* __restrict__ pm,
    const float* __restrict__ ps, u16* __restrict__ ypart, int c256)
{
    __shared__ u16 As[64 * 64];
    __shared__ u16 Bs[256 * 64];
    __shared__ float Red[64][4];
    __shared__ float Ms[64], Is[64];
    const int tid = threadIdx.x;
    const int l = tid & 63, w = tid >> 6;
    const int lr = l & 15, lh = l >> 4;
    const int kc = blockIdx.x;
    const int row0 = blockIdx.y * 64;
    const int kbase = kc * 512;
    const int srow = l >> 3, scol = ((l & 7) ^ (l >> 3)) * 8;

    // ---- global row stats from 64 per-tile partials ----
    {
        int row = tid & 63, part = tid >> 6;   // 4 parts x 16 entries
        const float* pmr = &pm[(size_t)(row0 + row) * 64 + part * 16];
        const float* psr = &ps[(size_t)(row0 + row) * 64 + part * 16];
        float M = -INFINITY;
        #pragma unroll
        for (int i = 0; i < 16; ++i) M = fmaxf(M, pmr[i]);
        Red[row][part] = M;
        __syncthreads();
        float Mg = fmaxf(fmaxf(Red[row][0], Red[row][1]),
                         fmaxf(Red[row][2], Red[row][3]));
        float S = 0.f;
        #pragma unroll
        for (int i = 0; i < 16; ++i) S += psr[i] * expf(pmr[i] - Mg);
        __syncthreads();
        Red[row][part] = S;
        __syncthreads();
        if (tid < 64) {
            float Sg = Red[tid][0] + Red[tid][1] + Red[tid][2] + Red[tid][3];
            Ms[tid] = Mg;               // this thread's row == tid
            Is[tid] = 1.0f / Sg;
        }
        __syncthreads();
    }

    float Mr[4], Ir[4];
    #pragma unroll
    for (int i = 0; i < 4; ++i) { int r = (tid >> 4) + i * 16; Mr[i] = Ms[r]; Ir[i] = Is[r]; }

    f32x4 acc[4][4] = {};

    for (int kt = 0; kt < 8; ++kt) {
        const int tcol = kc * 8 + kt;          // 64-col stats tile index
        __syncthreads();
        // stage A: w = exp(D + (M_t - M)) * (1/S) -> fp16, XOR-swizzled write
        #pragma unroll
        for (int i = 0; i < 4; ++i) {
            int idx = tid + i * 256;
            int r = idx >> 4, s4 = idx & 15;
            float coff = pm[(size_t)(row0 + r) * 64 + tcol] - Mr[i];
            size_t ga = (size_t)(row0 + r) * 4096 + kbase + kt * 64 + s4 * 4;
            ushort4 dv = *reinterpret_cast<const ushort4*>(&Lh[ga]);
            float e0 = expf(h2f(dv.x) + coff) * Ir[i];
            float e1 = expf(h2f(dv.y) + coff) * Ir[i];
            float e2 = expf(h2f(dv.z) + coff) * Ir[i];
            float e3 = expf(h2f(dv.w) + coff) * Ir[i];
            if (WRITE_W)
                *reinterpret_cast<float4*>(&Wout[ga]) = make_float4(e0, e1, e2, e3);
            ushort4 h;
            h.x = f2h(e0); h.y = f2h(e1); h.z = f2h(e2); h.w = f2h(e3);
            int dst = ((s4 >> 1) ^ (r & 7)) * 8 + (s4 & 1) * 4;
            *reinterpret_cast<ushort4*>(&As[r * 64 + dst]) = h;
        }
        // stage B: Vt rows c256..+256 x 64 k-cols (pre-swizzled source)
        #pragma unroll
        for (int i = 0; i < 8; ++i) {
            int r0 = w * 64 + i * 8;
            GLD16(&Vt[(size_t)(c256 + r0 + srow) * 4096 + kbase + kt * 64 + scol],
                  &Bs[r0 * 64]);
        }
        __syncthreads();
        #pragma unroll
        for (int kh = 0; kh < 2; ++kh) {
            short8 af[4], bfv[4];
            #pragma unroll
            for (int m = 0; m < 4; ++m)
                af[m] = *reinterpret_cast<const short8*>(
                    &As[(m * 16 + lr) * 64 + ((kh * 4 + lh) ^ (lr & 7)) * 8]);
            #pragma unroll
            for (int n = 0; n < 4; ++n)
                bfv[n] = *reinterpret_cast<const short8*>(
                    &Bs[(w * 64 + n * 16 + lr) * 64 + ((kh * 4 + lh) ^ (lr & 7)) * 8]);
            #pragma unroll
            for (int m = 0; m < 4; ++m)
                #pragma unroll
                for (int n = 0; n < 4; ++n)
                    acc[m][n] = MFMA_F16(af[m], bfv[n], acc[m][n]);
        }
    }

    #pragma unroll
    for (int m = 0; m < 4; ++m)
        #pragma unroll
        for (int n = 0; n < 4; ++n) {
            int rr = m * 16 + lh * 4;
            int col = w * 64 + n * 16 + lr;
            #pragma unroll
            for (int j = 0; j < 4; ++j)
                ypart[((size_t)kc * 4096 + row0 + rr + j) * 256 + col] = f2h(acc[m][n][j]);
        }
}

// y[:, c256..c256+256] = sum over 8 k-chunk fp16 partials (f32 accumulate)
__global__ __launch_bounds__(256) void reduce_y(const u16* __restrict__ ypart,
                                                float* __restrict__ y, int c256)
{
    int idx = blockIdx.x * 256 + threadIdx.x;
    int r = idx >> 6, c4 = (idx & 63) * 4;
    float s0 = 0.f, s1 = 0.f, s2 = 0.f, s3 = 0.f;
    #pragma unroll
    for (int kc = 0; kc < 8; ++kc) {
        ushort4 p = *reinterpret_cast<const ushort4*>(
            &ypart[((size_t)kc * 4096 + r) * 256 + c4]);
        s0 += h2f(p.x); s1 += h2f(p.y); s2 += h2f(p.z); s3 += h2f(p.w);
    }
    *reinterpret_cast<float4*>(&y[(size_t)r * 1024 + c256 + c4]) =
        make_float4(s0, s1, s2, s3);
}

extern "C" void kernel_launch(void* const* d_in, const int* in_sizes, int n_in,
                              void* d_out, int out_size, void* d_ws, size_t ws_size,
                              hipStream_t stream)
{
    const int n = 4096, d = 1024;
    const float* x  = (const float*)d_in[0];
    const float* WQ = (const float*)d_in[1];
    const float* WK = (const float*)d_in[2];
    const float* WV = (const float*)d_in[3];

    float* y = (float*)d_out;                  // [4096,1024]
    float* wout = y + (size_t)n * d;           // [4096,4096] final w (c=3 only)

    // ws layout. Lh region doubles as xh/Wh scratch: xh/Wh are consumed by
    // qkv8 BEFORE logits8 first writes Lh (stream-ordered).
    u16* Lh   = (u16*)d_ws;                    // [4096][4096] fp16 D  (33.5 MB)
    u16* xh   = Lh;                            // [4096,1024] fp16 (alias, dead early)
    u16* Wh   = Lh + (size_t)n * 1024;         // [3072,1024] fp16 (alias, dead early)
    u16* Qh   = Lh + (size_t)n * 4096;         // [4096,1024] fp16
    u16* Kh   = Qh  + (size_t)n * 1024;
    u16* Khn  = Kh  + (size_t)n * 1024;
    u16* Vt   = Khn + (size_t)n * 1024;        // [1024,4096] fp16 V^T
    u16* ypart = Vt + (size_t)d * 4096;        // [8][4096][256] fp16 (16 MB)
    float* pm = (float*)(ypart + (size_t)8 * n * 256);   // [4096][64] (1 MB)
    float* ps = pm + (size_t)n * 64;           // [4096][64] (1 MB)
    // total ws ~83.5 MB

    to_h<<<n * d / 1024, 256, 0, stream>>>(x, xh);
    to_h<<<d * d / 1024, 256, 0, stream>>>(WQ, Wh);
    to_h<<<d * d / 1024, 256, 0, stream>>>(WK, Wh + (size_t)d * 1024);
    to_h<<<d * d / 1024, 256, 0, stream>>>(WV, Wh + (size_t)2 * d * 1024);

    qkv8<<<192, 512, 0, stream>>>(xh, Wh, Qh, Kh, Khn, Vt);

    const int permv[4] = {0xE4, 0xB1, 0x4E, 0x1B};
    const int signv[4] = {0x0E, 0x08, 0x02, 0x04};

    for (int c = 0; c < 4; ++c) {
        logits8<<<256, 512, 0, stream>>>(Qh, Kh, Khn, Lh, pm, ps, permv[c], signv[c]);
        if (c == 3)
            pv_fused<true><<<dim3(8, 64), 256, 0, stream>>>(Lh, wout, Vt, pm, ps, ypart, c * 256);
        else
            pv_fused<false><<<dim3(8, 64), 256, 0, stream>>>(Lh, wout, Vt, pm, ps, ypart, c * 256);
        reduce_y<<<1024, 256, 0, stream>>>(ypart, y, c * 256);
    }
}